// Round 1
// baseline (17177.710 us; speedup 1.0000x reference)
//
#include <hip/hip_runtime.h>

#define NN 50000
#define NE 800000
#define HD 128
#define INN 11
#define NL 4
#define EPB 16

__device__ __forceinline__ float silu_f(float x) {
    return x / (1.0f + __expf(-x));
}

// ---------------- zero agg ----------------
__global__ __launch_bounds__(256) void zero_kernel(float4* __restrict__ p, int n4)
{
    int i = blockIdx.x * 256 + threadIdx.x;
    if (i < n4) p[i] = make_float4(0.f, 0.f, 0.f, 0.f);
}

// ---------------- embedding: h = h0 @ emb_w + emb_b ----------------
__global__ __launch_bounds__(256) void embed_kernel(
    const float* __restrict__ h0, const float* __restrict__ w,
    const float* __restrict__ b, float* __restrict__ h)
{
    int idx = blockIdx.x * 256 + threadIdx.x;
    if (idx >= NN * HD) return;
    int n = idx >> 7, j = idx & 127;
    float acc = b[j];
    #pragma unroll
    for (int k = 0; k < INN; ++k)
        acc += h0[n * INN + k] * w[k * HD + j];
    h[idx] = acc;
}

// ---------------- t = h @ Wa, u = h @ Wb (Wa=ew1 rows 0..127, Wb rows 128..255) ----------------
__global__ __launch_bounds__(256) void tu_kernel(
    const float* __restrict__ h, const float* __restrict__ ew1_l,
    float* __restrict__ t, float* __restrict__ u)
{
    __shared__ float lh[32][HD];
    int n0 = blockIdx.x * 32;
    for (int i = 0; i < 16; ++i) {
        int idx = i * 256 + threadIdx.x;
        int nl = idx >> 7, k = idx & 127;
        int n = n0 + nl;
        lh[nl][k] = (n < NN) ? h[n * HD + k] : 0.f;
    }
    __syncthreads();
    int nl = threadIdx.x >> 3;
    int jb = (threadIdx.x & 7) * 16;
    float ta[16], ua[16];
    #pragma unroll
    for (int q = 0; q < 16; ++q) { ta[q] = 0.f; ua[q] = 0.f; }
    const float4* Wa = (const float4*)(ew1_l) + (jb >> 2);
    const float4* Wb = (const float4*)(ew1_l + 128 * HD) + (jb >> 2);
    for (int k = 0; k < 128; ++k) {
        float hv = lh[nl][k];
        #pragma unroll
        for (int q4 = 0; q4 < 4; ++q4) {
            float4 wa = Wa[k * 32 + q4];
            float4 wb = Wb[k * 32 + q4];
            ta[q4*4+0] += hv * wa.x; ta[q4*4+1] += hv * wa.y;
            ta[q4*4+2] += hv * wa.z; ta[q4*4+3] += hv * wa.w;
            ua[q4*4+0] += hv * wb.x; ua[q4*4+1] += hv * wb.y;
            ua[q4*4+2] += hv * wb.z; ua[q4*4+3] += hv * wb.w;
        }
    }
    int n = n0 + nl;
    if (n < NN) {
        float4* tp = (float4*)(t + n * HD + jb);
        float4* up = (float4*)(u + n * HD + jb);
        #pragma unroll
        for (int q4 = 0; q4 < 4; ++q4) {
            tp[q4] = make_float4(ta[q4*4], ta[q4*4+1], ta[q4*4+2], ta[q4*4+3]);
            up[q4] = make_float4(ua[q4*4], ua[q4*4+1], ua[q4*4+2], ua[q4*4+3]);
        }
    }
}

// ---------------- fused edge model + scatter ----------------
// v = silu(t[row] + u[col] + radial*wr + ea@We + b1)   [EPB x 128]
// m = silu(v @ ew2 + b2) * edge_mask ; agg[row] += m (atomic)
__global__ __launch_bounds__(256) void edge_kernel(
    const float* __restrict__ t, const float* __restrict__ u,
    const float* __restrict__ x, const float* __restrict__ eattr,
    const float* __restrict__ emask, const int* __restrict__ ei,
    const float* __restrict__ ew1_l, const float* __restrict__ eb1_l,
    const float* __restrict__ ew2_l, const float* __restrict__ eb2_l,
    float* __restrict__ agg)
{
    __shared__ __attribute__((aligned(16))) float lwT[HD * 132]; // ew2^T, row stride 132
    __shared__ __attribute__((aligned(16))) float lv[EPB * HD];
    __shared__ int   ler[EPB], lec[EPB];
    __shared__ float lrad[EPB], lmask[EPB];
    __shared__ float4 lea[EPB];

    int e0 = blockIdx.x * EPB;

    // stage ew2 transposed
    for (int i = 0; i < 64; ++i) {
        int idx = i * 256 + threadIdx.x;
        int k = idx >> 7, j = idx & 127;
        lwT[j * 132 + k] = ew2_l[idx];
    }
    // stage per-edge scalars (and compute radial on the fly)
    if (threadIdx.x < EPB) {
        int e = e0 + threadIdx.x;
        if (e < NE) {
            int r = ei[e], c = ei[NE + e];
            ler[threadIdx.x] = r;
            lec[threadIdx.x] = c;
            float dx = x[3*r]   - x[3*c];
            float dy = x[3*r+1] - x[3*c+1];
            float dz = x[3*r+2] - x[3*c+2];
            lrad[threadIdx.x] = dx*dx + dy*dy + dz*dz;
            lmask[threadIdx.x] = emask[e];
            lea[threadIdx.x] = ((const float4*)eattr)[e];
        } else {
            ler[threadIdx.x] = 0; lec[threadIdx.x] = 0;
            lrad[threadIdx.x] = 0.f; lmask[threadIdx.x] = 0.f;
            lea[threadIdx.x] = make_float4(0.f, 0.f, 0.f, 0.f);
        }
    }
    __syncthreads();

    int j = threadIdx.x & 127;
    int eh = threadIdx.x >> 7; // 0 or 1
    {
        float wr  = ew1_l[256 * HD + j];
        float wa0 = ew1_l[257 * HD + j];
        float wa1 = ew1_l[258 * HD + j];
        float wa2 = ew1_l[259 * HD + j];
        float wa3 = ew1_l[260 * HD + j];
        float b1  = eb1_l[j];
        #pragma unroll
        for (int i = 0; i < 8; ++i) {
            int el = i * 2 + eh;
            float4 ea = lea[el];
            float val = t[ler[el] * HD + j] + u[lec[el] * HD + j]
                      + lrad[el] * wr
                      + ea.x * wa0 + ea.y * wa1 + ea.z * wa2 + ea.w * wa3 + b1;
            lv[el * HD + j] = silu_f(val);
        }
    }
    __syncthreads();

    float b2 = eb2_l[j];
    const float4* wT4 = (const float4*)(&lwT[j * 132]);
    const float4* v4  = (const float4*)lv;
    #pragma unroll
    for (int g = 0; g < 2; ++g) {
        int eb = eh * 8 + g * 4;
        float a0 = 0.f, a1 = 0.f, a2 = 0.f, a3 = 0.f;
        for (int k4 = 0; k4 < 32; ++k4) {
            float4 w  = wT4[k4];
            float4 p0 = v4[(eb+0) * 32 + k4];
            float4 p1 = v4[(eb+1) * 32 + k4];
            float4 p2 = v4[(eb+2) * 32 + k4];
            float4 p3 = v4[(eb+3) * 32 + k4];
            a0 += w.x*p0.x + w.y*p0.y + w.z*p0.z + w.w*p0.w;
            a1 += w.x*p1.x + w.y*p1.y + w.z*p1.z + w.w*p1.w;
            a2 += w.x*p2.x + w.y*p2.y + w.z*p2.z + w.w*p2.w;
            a3 += w.x*p3.x + w.y*p3.y + w.z*p3.z + w.w*p3.w;
        }
        float m0 = silu_f(a0 + b2) * lmask[eb+0];
        float m1 = silu_f(a1 + b2) * lmask[eb+1];
        float m2 = silu_f(a2 + b2) * lmask[eb+2];
        float m3 = silu_f(a3 + b2) * lmask[eb+3];
        if (e0 + eb + 0 < NE) atomicAdd(&agg[ler[eb+0] * HD + j], m0);
        if (e0 + eb + 1 < NE) atomicAdd(&agg[ler[eb+1] * HD + j], m1);
        if (e0 + eb + 2 < NE) atomicAdd(&agg[ler[eb+2] * HD + j], m2);
        if (e0 + eb + 3 < NE) atomicAdd(&agg[ler[eb+3] * HD + j], m3);
    }
}

// ---------------- node MLP layer 1: q = silu([h, agg, h0] @ nw1 + b1) ----------------
__global__ __launch_bounds__(256) void nk1_kernel(
    const float* __restrict__ h, const float* __restrict__ agg,
    const float* __restrict__ h0,
    const float* __restrict__ nw1_l, const float* __restrict__ nb1_l,
    float* __restrict__ qout)
{
    __shared__ float lh[32][HD];
    __shared__ float la[32][HD];
    __shared__ float l0[32][12];
    int n0 = blockIdx.x * 32;
    for (int i = 0; i < 16; ++i) {
        int idx = i * 256 + threadIdx.x;
        int nl = idx >> 7, k = idx & 127;
        int n = n0 + nl;
        lh[nl][k] = (n < NN) ? h[n * HD + k] : 0.f;
        la[nl][k] = (n < NN) ? agg[n * HD + k] : 0.f;
    }
    for (int i = 0; i < 2; ++i) {
        int idx = i * 256 + threadIdx.x;
        if (idx < 32 * INN) {
            int nl = idx / INN, k = idx - nl * INN;
            int n = n0 + nl;
            l0[nl][k] = (n < NN) ? h0[n * INN + k] : 0.f;
        }
    }
    __syncthreads();
    int nl = threadIdx.x >> 3;
    int jb = (threadIdx.x & 7) * 16;
    float acc[16];
    #pragma unroll
    for (int q = 0; q < 16; ++q) acc[q] = nb1_l[jb + q];
    const float4* W = (const float4*)nw1_l + (jb >> 2);
    for (int k = 0; k < 128; ++k) {
        float hv = lh[nl][k];
        #pragma unroll
        for (int q4 = 0; q4 < 4; ++q4) {
            float4 w = W[k * 32 + q4];
            acc[q4*4+0] += hv * w.x; acc[q4*4+1] += hv * w.y;
            acc[q4*4+2] += hv * w.z; acc[q4*4+3] += hv * w.w;
        }
    }
    const float4* W2 = W + 128 * 32;
    for (int k = 0; k < 128; ++k) {
        float av = la[nl][k];
        #pragma unroll
        for (int q4 = 0; q4 < 4; ++q4) {
            float4 w = W2[k * 32 + q4];
            acc[q4*4+0] += av * w.x; acc[q4*4+1] += av * w.y;
            acc[q4*4+2] += av * w.z; acc[q4*4+3] += av * w.w;
        }
    }
    const float4* W3 = W2 + 128 * 32;
    #pragma unroll
    for (int k = 0; k < INN; ++k) {
        float zv = l0[nl][k];
        #pragma unroll
        for (int q4 = 0; q4 < 4; ++q4) {
            float4 w = W3[k * 32 + q4];
            acc[q4*4+0] += zv * w.x; acc[q4*4+1] += zv * w.y;
            acc[q4*4+2] += zv * w.z; acc[q4*4+3] += zv * w.w;
        }
    }
    int n = n0 + nl;
    if (n < NN) {
        float4* qp = (float4*)(qout + n * HD + jb);
        #pragma unroll
        for (int q4 = 0; q4 < 4; ++q4)
            qp[q4] = make_float4(silu_f(acc[q4*4+0]), silu_f(acc[q4*4+1]),
                                 silu_f(acc[q4*4+2]), silu_f(acc[q4*4+3]));
    }
}

// ---------------- node MLP layer 2 + residual: h += q @ nw2 + b2 ----------------
__global__ __launch_bounds__(256) void nk2_kernel(
    const float* __restrict__ q, const float* __restrict__ nw2_l,
    const float* __restrict__ nb2_l, float* __restrict__ h)
{
    __shared__ float lq[32][HD];
    int n0 = blockIdx.x * 32;
    for (int i = 0; i < 16; ++i) {
        int idx = i * 256 + threadIdx.x;
        int nl = idx >> 7, k = idx & 127;
        int n = n0 + nl;
        lq[nl][k] = (n < NN) ? q[n * HD + k] : 0.f;
    }
    __syncthreads();
    int nl = threadIdx.x >> 3;
    int jb = (threadIdx.x & 7) * 16;
    float acc[16];
    #pragma unroll
    for (int qq = 0; qq < 16; ++qq) acc[qq] = nb2_l[jb + qq];
    const float4* W = (const float4*)nw2_l + (jb >> 2);
    for (int k = 0; k < 128; ++k) {
        float qv = lq[nl][k];
        #pragma unroll
        for (int q4 = 0; q4 < 4; ++q4) {
            float4 w = W[k * 32 + q4];
            acc[q4*4+0] += qv * w.x; acc[q4*4+1] += qv * w.y;
            acc[q4*4+2] += qv * w.z; acc[q4*4+3] += qv * w.w;
        }
    }
    int n = n0 + nl;
    if (n < NN) {
        float4* hp = (float4*)(h + n * HD + jb);
        #pragma unroll
        for (int q4 = 0; q4 < 4; ++q4) {
            float4 o = hp[q4];
            hp[q4] = make_float4(o.x + acc[q4*4+0], o.y + acc[q4*4+1],
                                 o.z + acc[q4*4+2], o.w + acc[q4*4+3]);
        }
    }
}

extern "C" void kernel_launch(void* const* d_in, const int* in_sizes, int n_in,
                              void* d_out, int out_size, void* d_ws, size_t ws_size,
                              hipStream_t stream)
{
    const float* h0    = (const float*)d_in[0];
    const float* x     = (const float*)d_in[1];
    const int*   ei    = (const int*)d_in[2];
    const float* eattr = (const float*)d_in[3];
    const float* emask = (const float*)d_in[5];   // node_mask (d_in[4]) unused by reference
    const float* emb_w = (const float*)d_in[7];
    const float* emb_b = (const float*)d_in[8];
    const float* ew1   = (const float*)d_in[9];
    const float* eb1   = (const float*)d_in[10];
    const float* ew2   = (const float*)d_in[11];
    const float* eb2   = (const float*)d_in[12];
    const float* nw1   = (const float*)d_in[13];
    const float* nb1   = (const float*)d_in[14];
    const float* nw2   = (const float*)d_in[15];
    const float* nb2   = (const float*)d_in[16];

    float* h  = (float*)d_out;          // h lives in d_out, updated in place
    float* ws = (float*)d_ws;
    float* t   = ws;                    // NN*HD
    float* u   = t + NN * HD;           // NN*HD
    float* agg = u + NN * HD;           // NN*HD
    float* q   = t;                     // alias t (dead after edge_kernel)

    embed_kernel<<<(NN * HD + 255) / 256, 256, 0, stream>>>(h0, emb_w, emb_b, h);

    for (int l = 0; l < NL; ++l) {
        tu_kernel<<<(NN + 31) / 32, 256, 0, stream>>>(h, ew1 + l * 261 * HD, t, u);
        zero_kernel<<<(NN * HD / 4 + 255) / 256, 256, 0, stream>>>((float4*)agg, NN * HD / 4);
        edge_kernel<<<NE / EPB, 256, 0, stream>>>(t, u, x, eattr, emask, ei,
            ew1 + l * 261 * HD, eb1 + l * HD, ew2 + l * HD * HD, eb2 + l * HD, agg);
        nk1_kernel<<<(NN + 31) / 32, 256, 0, stream>>>(h, agg, h0,
            nw1 + l * 267 * HD, nb1 + l * HD, q);
        nk2_kernel<<<(NN + 31) / 32, 256, 0, stream>>>(q, nw2 + l * HD * HD, nb2 + l * HD, h);
    }
}

// Round 4
// 3744.831 us; speedup vs baseline: 4.5870x; 4.5870x over previous
//
#include <hip/hip_runtime.h>

#define NN 50000
#define NE 800000
#define HD 128
#define INN 11
#define NL 4
#define EGROUPS (NE / 64)   // 12500

typedef __attribute__((ext_vector_type(8))) short bf16x8;
typedef __attribute__((ext_vector_type(4))) float f32x4;

__device__ __forceinline__ float silu_f(float x) {
    return x / (1.0f + __expf(-x));
}

// fp32 -> bf16 round-to-nearest-even
__device__ __forceinline__ short f2bf(float x) {
    unsigned u = __float_as_uint(x);
    return (short)((u + 0x7FFFu + ((u >> 16) & 1u)) >> 16);
}

#define LOAD_FMA(hv, ptr) { \
    float4 w0_ = *(const float4*)(ptr); \
    float4 w1_ = *(const float4*)((ptr) + 4); \
    a0 += (hv) * w0_.x; a1 += (hv) * w0_.y; a2 += (hv) * w0_.z; a3 += (hv) * w0_.w; \
    a4 += (hv) * w1_.x; a5 += (hv) * w1_.y; a6 += (hv) * w1_.z; a7 += (hv) * w1_.w; }

// ---------------- zero agg ----------------
__global__ __launch_bounds__(256) void zero_kernel(float4* __restrict__ p, int n4)
{
    int i = blockIdx.x * 256 + threadIdx.x;
    if (i < n4) p[i] = make_float4(0.f, 0.f, 0.f, 0.f);
}

// ---------------- embedding: h = h0 @ emb_w + emb_b ----------------
__global__ __launch_bounds__(256) void embed_kernel(
    const float* __restrict__ h0, const float* __restrict__ w,
    const float* __restrict__ b, float* __restrict__ h)
{
    int idx = blockIdx.x * 256 + threadIdx.x;
    if (idx >= NN * HD) return;
    int n = idx >> 7, j = idx & 127;
    float acc = b[j];
    #pragma unroll
    for (int k = 0; k < INN; ++k)
        acc += h0[n * INN + k] * w[k * HD + j];
    h[idx] = acc;
}

// ---------------- t = h @ Wa, u = h @ Wb ----------------
// 8 nodes/block; thread = (node, 8-col strip across t|u). Scalar accumulators.
__global__ __launch_bounds__(256, 2) void tu_kernel(
    const float* __restrict__ h, const float* __restrict__ ew1_l,
    float* __restrict__ t, float* __restrict__ u)
{
    __shared__ float lh[8][132];
    int n0 = blockIdx.x * 8;
    for (int i = threadIdx.x; i < 8 * 128; i += 256) {
        int nl = i >> 7, k = i & 127;
        lh[nl][k] = h[(n0 + nl) * HD + k];
    }
    __syncthreads();
    int nl = threadIdx.x >> 5;
    int c0 = (threadIdx.x & 31) * 8;
    const float* wbase = (c0 < 128) ? (ew1_l + c0) : (ew1_l + 128 * HD + (c0 - 128));
    float*       obase = (c0 < 128) ? (t + (n0 + nl) * HD + c0)
                                    : (u + (n0 + nl) * HD + (c0 - 128));
    float a0 = 0.f, a1 = 0.f, a2 = 0.f, a3 = 0.f, a4 = 0.f, a5 = 0.f, a6 = 0.f, a7 = 0.f;
    for (int k = 0; k < 128; ++k) {
        float hv = lh[nl][k];
        LOAD_FMA(hv, wbase + k * HD);
    }
    *(float4*)(obase)     = make_float4(a0, a1, a2, a3);
    *(float4*)(obase + 4) = make_float4(a4, a5, a6, a7);
}

// ---------------- fused edge model + MFMA GEMM + scatter ----------------
__global__ __launch_bounds__(256, 2) void edge_mfma_kernel(
    const float* __restrict__ t, const float* __restrict__ u,
    const float* __restrict__ x, const float* __restrict__ eattr,
    const float* __restrict__ emask, const int* __restrict__ ei,
    const float* __restrict__ ew1_l, const float* __restrict__ eb1_l,
    const float* __restrict__ ew2_l, const float* __restrict__ eb2_l,
    float* __restrict__ agg)
{
    __shared__ __align__(16) short BT[128 * 136];  // bf16(ew2)^T, padded stride 136
    __shared__ __align__(16) short VA[64 * 136];   // bf16 v tile
    __shared__ int    s_r[64];
    __shared__ int    s_c[64];
    __shared__ float  s_rad[64];
    __shared__ float  s_mask[64];
    __shared__ float4 s_ea[64];
    __shared__ float  s_b2[128];

    // stage BT = bf16(ew2)^T once per block
    for (int i = threadIdx.x; i < 128 * 128; i += 256) {
        int k = i >> 7, n = i & 127;
        BT[n * 136 + k] = f2bf(ew2_l[i]);
    }
    if (threadIdx.x < 128) s_b2[threadIdx.x] = eb2_l[threadIdx.x];

    int j  = threadIdx.x & 127;
    int eh = threadIdx.x >> 7;
    float wr  = ew1_l[256 * HD + j];
    float wa0 = ew1_l[257 * HD + j];
    float wa1 = ew1_l[258 * HD + j];
    float wa2 = ew1_l[259 * HD + j];
    float wa3 = ew1_l[260 * HD + j];
    float b1  = eb1_l[j];

    int lane = threadIdx.x & 63;
    int wv   = threadIdx.x >> 6;   // wave 0..3
    int ln15 = lane & 15;
    int quad = lane >> 4;
    int mbase = wv * 16;

    for (int g = blockIdx.x; g < EGROUPS; g += gridDim.x) {
        __syncthreads();   // protect prev iter's LDS reads (and BT staging on iter 0)
        if (threadIdx.x < 64) {
            int e = g * 64 + threadIdx.x;
            int r = ei[e], c = ei[NE + e];
            s_r[threadIdx.x] = r;
            s_c[threadIdx.x] = c;
            float dx = x[3 * r]     - x[3 * c];
            float dy = x[3 * r + 1] - x[3 * c + 1];
            float dz = x[3 * r + 2] - x[3 * c + 2];
            s_rad[threadIdx.x]  = dx * dx + dy * dy + dz * dz;
            s_mask[threadIdx.x] = emask[e];
            s_ea[threadIdx.x]   = ((const float4*)eattr)[e];
        }
        __syncthreads();

        // v = silu(t[row] + u[col] + rad*wr + ea@We + b1), bf16 into VA
        for (int i = 0; i < 32; ++i) {
            int el = i * 2 + eh;
            float4 ea = s_ea[el];
            float val = t[s_r[el] * HD + j] + u[s_c[el] * HD + j]
                      + s_rad[el] * wr
                      + ea.x * wa0 + ea.y * wa1 + ea.z * wa2 + ea.w * wa3 + b1;
            VA[el * 136 + j] = f2bf(silu_f(val));
        }
        __syncthreads();

        // wave wv: rows mbase..mbase+15, all 128 cols, K=128
        bf16x8 afr[4];
        #pragma unroll
        for (int kt = 0; kt < 4; ++kt)
            afr[kt] = *(const bf16x8*)&VA[(mbase + ln15) * 136 + kt * 32 + quad * 8];

        #pragma unroll
        for (int ct = 0; ct < 8; ++ct) {
            f32x4 acc = {0.f, 0.f, 0.f, 0.f};
            #pragma unroll
            for (int kt = 0; kt < 4; ++kt) {
                bf16x8 bfr = *(const bf16x8*)&BT[(ct * 16 + ln15) * 136 + kt * 32 + quad * 8];
                acc = __builtin_amdgcn_mfma_f32_16x16x32_bf16(afr[kt], bfr, acc, 0, 0, 0);
            }
            int col = ct * 16 + ln15;
            float b2c = s_b2[col];
            #pragma unroll
            for (int r4 = 0; r4 < 4; ++r4) {
                int em = mbase + quad * 4 + r4;
                float mval = silu_f(acc[r4] + b2c) * s_mask[em];
                atomicAdd(&agg[s_r[em] * HD + col], mval);
            }
        }
    }
}

// ---------------- node MLP layer 1: q = silu([h, agg, h0] @ nw1 + b1) ----------------
__global__ __launch_bounds__(256, 2) void nk1_kernel(
    const float* __restrict__ h, const float* __restrict__ agg,
    const float* __restrict__ h0,
    const float* __restrict__ nw1_l, const float* __restrict__ nb1_l,
    float* __restrict__ qout)
{
    __shared__ float lh[16][132];
    __shared__ float la[16][132];
    __shared__ float l0[16][12];
    int n0 = blockIdx.x * 16;
    for (int i = threadIdx.x; i < 16 * 128; i += 256) {
        int nl = i >> 7, k = i & 127;
        lh[nl][k] = h[(n0 + nl) * HD + k];
        la[nl][k] = agg[(n0 + nl) * HD + k];
    }
    for (int i = threadIdx.x; i < 16 * INN; i += 256) {
        int nl = i / INN, k = i - nl * INN;
        l0[nl][k] = h0[(n0 + nl) * INN + k];
    }
    __syncthreads();
    int nl = threadIdx.x >> 4;
    int c0 = (threadIdx.x & 15) * 8;
    float4 bv0 = *(const float4*)(nb1_l + c0);
    float4 bv1 = *(const float4*)(nb1_l + c0 + 4);
    float a0 = bv0.x, a1 = bv0.y, a2 = bv0.z, a3 = bv0.w;
    float a4 = bv1.x, a5 = bv1.y, a6 = bv1.z, a7 = bv1.w;
    const float* wp = nw1_l + c0;
    for (int k = 0; k < 128; ++k) {
        float hv = lh[nl][k];
        LOAD_FMA(hv, wp + k * HD);
    }
    wp += 128 * HD;
    for (int k = 0; k < 128; ++k) {
        float av = la[nl][k];
        LOAD_FMA(av, wp + k * HD);
    }
    wp += 128 * HD;
    #pragma unroll
    for (int k = 0; k < INN; ++k) {
        float zv = l0[nl][k];
        LOAD_FMA(zv, wp + k * HD);
    }
    float* op = qout + (n0 + nl) * HD + c0;
    *(float4*)(op)     = make_float4(silu_f(a0), silu_f(a1), silu_f(a2), silu_f(a3));
    *(float4*)(op + 4) = make_float4(silu_f(a4), silu_f(a5), silu_f(a6), silu_f(a7));
}

// ---------------- node MLP layer 2 + residual: h += q @ nw2 + b2 ----------------
__global__ __launch_bounds__(256, 2) void nk2_kernel(
    const float* __restrict__ q, const float* __restrict__ nw2_l,
    const float* __restrict__ nb2_l, float* __restrict__ h)
{
    __shared__ float lq[16][132];
    int n0 = blockIdx.x * 16;
    for (int i = threadIdx.x; i < 16 * 128; i += 256) {
        int nl = i >> 7, k = i & 127;
        lq[nl][k] = q[(n0 + nl) * HD + k];
    }
    __syncthreads();
    int nl = threadIdx.x >> 4;
    int c0 = (threadIdx.x & 15) * 8;
    float4 bv0 = *(const float4*)(nb2_l + c0);
    float4 bv1 = *(const float4*)(nb2_l + c0 + 4);
    float a0 = bv0.x, a1 = bv0.y, a2 = bv0.z, a3 = bv0.w;
    float a4 = bv1.x, a5 = bv1.y, a6 = bv1.z, a7 = bv1.w;
    const float* wp = nw2_l + c0;
    for (int k = 0; k < 128; ++k) {
        float qv = lq[nl][k];
        LOAD_FMA(qv, wp + k * HD);
    }
    float* hp = h + (n0 + nl) * HD + c0;
    float4 o0 = *(float4*)(hp);
    float4 o1 = *(float4*)(hp + 4);
    *(float4*)(hp)     = make_float4(o0.x + a0, o0.y + a1, o0.z + a2, o0.w + a3);
    *(float4*)(hp + 4) = make_float4(o1.x + a4, o1.y + a5, o1.z + a6, o1.w + a7);
}

extern "C" void kernel_launch(void* const* d_in, const int* in_sizes, int n_in,
                              void* d_out, int out_size, void* d_ws, size_t ws_size,
                              hipStream_t stream)
{
    const float* h0    = (const float*)d_in[0];
    const float* x     = (const float*)d_in[1];
    const int*   ei    = (const int*)d_in[2];
    const float* eattr = (const float*)d_in[3];
    const float* emask = (const float*)d_in[5];
    const float* emb_w = (const float*)d_in[7];
    const float* emb_b = (const float*)d_in[8];
    const float* ew1   = (const float*)d_in[9];
    const float* eb1   = (const float*)d_in[10];
    const float* ew2   = (const float*)d_in[11];
    const float* eb2   = (const float*)d_in[12];
    const float* nw1   = (const float*)d_in[13];
    const float* nb1   = (const float*)d_in[14];
    const float* nw2   = (const float*)d_in[15];
    const float* nb2   = (const float*)d_in[16];

    float* h   = (float*)d_out;
    float* ws  = (float*)d_ws;
    float* t   = ws;                 // NN*HD
    float* u   = t + NN * HD;        // NN*HD
    float* agg = u + NN * HD;        // NN*HD
    float* q   = t;                  // alias t (dead after edge kernel)

    embed_kernel<<<(NN * HD + 255) / 256, 256, 0, stream>>>(h0, emb_w, emb_b, h);

    for (int l = 0; l < NL; ++l) {
        tu_kernel<<<NN / 8, 256, 0, stream>>>(h, ew1 + l * 261 * HD, t, u);
        zero_kernel<<<(NN * HD / 4 + 255) / 256, 256, 0, stream>>>((float4*)agg, NN * HD / 4);
        edge_mfma_kernel<<<1024, 256, 0, stream>>>(t, u, x, eattr, emask, ei,
            ew1 + l * 261 * HD, eb1 + l * HD, ew2 + l * HD * HD, eb2 + l * HD, agg);
        nk1_kernel<<<NN / 16, 256, 0, stream>>>(h, agg, h0,
            nw1 + l * 267 * HD, nb1 + l * HD, q);
        nk2_kernel<<<NN / 16, 256, 0, stream>>>(q, nw2 + l * HD * HD, nb2 + l * HD, h);
    }
}

// Round 5
// 2564.097 us; speedup vs baseline: 6.6993x; 1.4605x over previous
//
#include <hip/hip_runtime.h>

#define NN 50000
#define NE 800000
#define HD 128
#define INN 11
#define NL 4
#define NG16 3125        // 16-row node groups (50000/16 exact)
#define EGROUPS 12500    // 64-edge groups (800000/64 exact)
#define K1S 296          // nk1 padded K stride (bank-conflict-free for b128)

typedef __attribute__((ext_vector_type(8))) short bf16x8;
typedef __attribute__((ext_vector_type(4))) float f32x4;

__device__ __forceinline__ float silu_f(float x) { return x / (1.0f + __expf(-x)); }

__device__ __forceinline__ short f2bf(float x) {
    unsigned u = __float_as_uint(x);
    return (short)((u + 0x7FFFu + ((u >> 16) & 1u)) >> 16);
}
__device__ __forceinline__ unsigned f2bf2(float a, float b) {
    return ((unsigned)(unsigned short)f2bf(b) << 16) | (unsigned)(unsigned short)f2bf(a);
}
__device__ __forceinline__ float bf2f(short s) {
    return __uint_as_float(((unsigned)(unsigned short)s) << 16);
}
__device__ __forceinline__ bf16x8 pack8(float4 a, float4 b) {
    bf16x8 r;
    r[0] = f2bf(a.x); r[1] = f2bf(a.y); r[2] = f2bf(a.z); r[3] = f2bf(a.w);
    r[4] = f2bf(b.x); r[5] = f2bf(b.y); r[6] = f2bf(b.z); r[7] = f2bf(b.w);
    return r;
}

// ---------------- embedding: h = h0 @ emb_w + emb_b ----------------
__global__ __launch_bounds__(256) void embed_kernel(
    const float* __restrict__ h0, const float* __restrict__ w,
    const float* __restrict__ b, float* __restrict__ h)
{
    int idx = blockIdx.x * 256 + threadIdx.x;
    if (idx >= NN * HD) return;
    int n = idx >> 7, j = idx & 127;
    float acc = b[j];
    #pragma unroll
    for (int k = 0; k < INN; ++k)
        acc += h0[n * INN + k] * w[k * HD + j];
    h[idx] = acc;
}

// ---------------- CSR build ----------------
__global__ __launch_bounds__(256) void csr_zero(int* __restrict__ cnt)
{
    int i = blockIdx.x * 256 + threadIdx.x;
    if (i < NN) cnt[i] = 0;
}

__global__ __launch_bounds__(256) void csr_hist(const int* __restrict__ ei, int* __restrict__ cnt)
{
    int e = blockIdx.x * 256 + threadIdx.x;
    atomicAdd(&cnt[ei[e]], 1);
}

__global__ __launch_bounds__(1024) void csr_scan(
    const int* __restrict__ cnt, int* __restrict__ rowptr, int* __restrict__ cursor)
{
    __shared__ int part[1024];
    int t = threadIdx.x;
    int base = t * 49;                       // 1024*49 = 50176 >= NN
    int s = 0;
    for (int i = 0; i < 49; ++i) { int j = base + i; if (j < NN) s += cnt[j]; }
    part[t] = s;
    __syncthreads();
    for (int off = 1; off < 1024; off <<= 1) {
        int v = (t >= off) ? part[t - off] : 0;
        __syncthreads();
        part[t] += v;
        __syncthreads();
    }
    int run = (t == 0) ? 0 : part[t - 1];
    for (int i = 0; i < 49; ++i) {
        int j = base + i;
        if (j < NN) { rowptr[j] = run; cursor[j] = run; run += cnt[j]; }
    }
    if (t == 1023) rowptr[NN] = part[1023];
}

__global__ __launch_bounds__(256) void csr_fill(
    const int* __restrict__ ei, int* __restrict__ cursor, int* __restrict__ eidx)
{
    int e = blockIdx.x * 256 + threadIdx.x;
    int r = ei[e];
    int p = atomicAdd(&cursor[r], 1);
    eidx[p] = e;
}

// ---------------- t|u = h @ ew1[0:256] (MFMA, bf16 out) ----------------
// gridDim.y: 0 -> t (Wa rows 0..127), 1 -> u (Wb rows 128..255)
__global__ __launch_bounds__(256) void tu_mfma(
    const float* __restrict__ h, const float* __restrict__ ew1_l,
    short* __restrict__ tb, short* __restrict__ ub)
{
    __shared__ __align__(16) short BT[128 * 136];  // 34.8 KB
    const float* wsrc = ew1_l + (blockIdx.y ? 128 * HD : 0);
    short* outp = blockIdx.y ? ub : tb;
    for (int i = threadIdx.x; i < 128 * 128; i += 256) {
        int c = i >> 7, k = i & 127;
        BT[c * 136 + k] = f2bf(wsrc[k * HD + c]);
    }
    int wv = threadIdx.x >> 6, lane = threadIdx.x & 63;
    int ln15 = lane & 15, quad = lane >> 4;
    int g = blockIdx.x * 4 + wv;
    __syncthreads();
    if (g >= NG16) return;

    int row = g * 16 + ln15;
    const float* hrow = h + row * HD;
    bf16x8 afr[4];
    #pragma unroll
    for (int kt = 0; kt < 4; ++kt) {
        float4 x0 = *(const float4*)(hrow + kt * 32 + quad * 8);
        float4 x1 = *(const float4*)(hrow + kt * 32 + quad * 8 + 4);
        afr[kt] = pack8(x0, x1);
    }
    #pragma unroll
    for (int ct = 0; ct < 8; ++ct) {
        f32x4 acc = {0.f, 0.f, 0.f, 0.f};
        #pragma unroll
        for (int kt = 0; kt < 4; ++kt) {
            bf16x8 bfr = *(const bf16x8*)&BT[(ct * 16 + ln15) * 136 + kt * 32 + quad * 8];
            acc = __builtin_amdgcn_mfma_f32_16x16x32_bf16(afr[kt], bfr, acc, 0, 0, 0);
        }
        int col = ct * 16 + ln15;
        #pragma unroll
        for (int r4 = 0; r4 < 4; ++r4) {
            int orow = g * 16 + quad * 4 + r4;
            outp[orow * HD + col] = f2bf(acc[r4]);
        }
    }
}

// ---------------- fused edge model + MFMA GEMM -> m (bf16, no atomics) ----------------
__global__ __launch_bounds__(256, 2) void edge_m_kernel(
    const short* __restrict__ tb, const short* __restrict__ ub,
    const float* __restrict__ x, const float* __restrict__ eattr,
    const float* __restrict__ emask, const int* __restrict__ ei,
    const float* __restrict__ ew1_l, const float* __restrict__ eb1_l,
    const float* __restrict__ ew2_l, const float* __restrict__ eb2_l,
    short* __restrict__ m)
{
    __shared__ __align__(16) short BT[128 * 136];  // bf16(ew2)^T
    __shared__ __align__(16) short VA[64 * 136];   // bf16 v tile
    __shared__ int    s_r[64];
    __shared__ int    s_c[64];
    __shared__ float  s_rad[64];
    __shared__ float  s_mask[64];
    __shared__ float4 s_ea[64];
    __shared__ float  s_b2[128];

    for (int i = threadIdx.x; i < 128 * 128; i += 256) {
        int k = i >> 7, n = i & 127;
        BT[n * 136 + k] = f2bf(ew2_l[i]);
    }
    if (threadIdx.x < 128) s_b2[threadIdx.x] = eb2_l[threadIdx.x];

    int j  = threadIdx.x & 127;
    int eh = threadIdx.x >> 7;
    float wr  = ew1_l[256 * HD + j];
    float wa0 = ew1_l[257 * HD + j];
    float wa1 = ew1_l[258 * HD + j];
    float wa2 = ew1_l[259 * HD + j];
    float wa3 = ew1_l[260 * HD + j];
    float b1  = eb1_l[j];

    int lane = threadIdx.x & 63;
    int wv   = threadIdx.x >> 6;
    int ln15 = lane & 15;
    int quad = lane >> 4;
    int mbase = wv * 16;

    for (int g = blockIdx.x; g < EGROUPS; g += gridDim.x) {
        __syncthreads();
        if (threadIdx.x < 64) {
            int e = g * 64 + threadIdx.x;
            int r = ei[e], c = ei[NE + e];
            s_r[threadIdx.x] = r;
            s_c[threadIdx.x] = c;
            float dx = x[3 * r]     - x[3 * c];
            float dy = x[3 * r + 1] - x[3 * c + 1];
            float dz = x[3 * r + 2] - x[3 * c + 2];
            s_rad[threadIdx.x]  = dx * dx + dy * dy + dz * dz;
            s_mask[threadIdx.x] = emask[e];
            s_ea[threadIdx.x]   = ((const float4*)eattr)[e];
        }
        __syncthreads();

        for (int i = 0; i < 32; ++i) {
            int el = i * 2 + eh;
            float4 ea = s_ea[el];
            float val = bf2f(tb[s_r[el] * HD + j]) + bf2f(ub[s_c[el] * HD + j])
                      + s_rad[el] * wr
                      + ea.x * wa0 + ea.y * wa1 + ea.z * wa2 + ea.w * wa3 + b1;
            VA[el * 136 + j] = f2bf(silu_f(val));
        }
        __syncthreads();

        bf16x8 afr[4];
        #pragma unroll
        for (int kt = 0; kt < 4; ++kt)
            afr[kt] = *(const bf16x8*)&VA[(mbase + ln15) * 136 + kt * 32 + quad * 8];

        #pragma unroll
        for (int ct = 0; ct < 8; ++ct) {
            f32x4 acc = {0.f, 0.f, 0.f, 0.f};
            #pragma unroll
            for (int kt = 0; kt < 4; ++kt) {
                bf16x8 bfr = *(const bf16x8*)&BT[(ct * 16 + ln15) * 136 + kt * 32 + quad * 8];
                acc = __builtin_amdgcn_mfma_f32_16x16x32_bf16(afr[kt], bfr, acc, 0, 0, 0);
            }
            int col = ct * 16 + ln15;
            float b2c = s_b2[col];
            #pragma unroll
            for (int r4 = 0; r4 < 4; ++r4) {
                int em = mbase + quad * 4 + r4;
                m[(g * 64 + em) * HD + col] = f2bf(silu_f(acc[r4] + b2c) * s_mask[em]);
            }
        }
    }
}

// ---------------- agg[n] = sum of m rows via CSR (one wave per node) ----------------
__global__ __launch_bounds__(256) void agg_gather(
    const short* __restrict__ m, const int* __restrict__ rowptr,
    const int* __restrict__ eidx, float* __restrict__ agg)
{
    int n = blockIdx.x * 4 + (threadIdx.x >> 6);
    int lane = threadIdx.x & 63;
    int s = rowptr[n], e = rowptr[n + 1];
    const unsigned* m4 = (const unsigned*)m;
    float a0 = 0.f, a1 = 0.f, b0 = 0.f, b1 = 0.f;
    int p = s;
    for (; p + 1 < e; p += 2) {
        unsigned u0 = m4[eidx[p] * 64 + lane];
        unsigned u1 = m4[eidx[p + 1] * 64 + lane];
        a0 += __uint_as_float(u0 << 16);
        a1 += __uint_as_float(u0 & 0xFFFF0000u);
        b0 += __uint_as_float(u1 << 16);
        b1 += __uint_as_float(u1 & 0xFFFF0000u);
    }
    if (p < e) {
        unsigned u0 = m4[eidx[p] * 64 + lane];
        a0 += __uint_as_float(u0 << 16);
        a1 += __uint_as_float(u0 & 0xFFFF0000u);
    }
    *(float2*)(agg + n * HD + lane * 2) = make_float2(a0 + b0, a1 + b1);
}

// ---------------- node MLP layer 1 (MFMA): q = silu([h,agg,h0]@nw1 + b1), bf16 out ----
// gridDim.y selects 64-col half.
__global__ __launch_bounds__(256) void nk1_mfma(
    const float* __restrict__ h, const float* __restrict__ agg,
    const float* __restrict__ h0,
    const float* __restrict__ nw1_l, const float* __restrict__ nb1_l,
    short* __restrict__ qb)
{
    __shared__ __align__(16) short BT[64 * K1S];  // 37.9 KB
    int c0 = blockIdx.y * 64;
    for (int i = threadIdx.x; i < 64 * 288; i += 256) {
        int c = i / 288, k = i - c * 288;
        BT[c * K1S + k] = (k < 267) ? f2bf(nw1_l[k * HD + c0 + c]) : (short)0;
    }
    int wv = threadIdx.x >> 6, lane = threadIdx.x & 63;
    int ln15 = lane & 15, quad = lane >> 4;
    int g = blockIdx.x * 4 + wv;
    __syncthreads();
    if (g >= NG16) return;

    int row = g * 16 + ln15;
    const float* hrow = h + row * HD;
    const float* arow = agg + row * HD;
    bf16x8 afr[9];
    #pragma unroll
    for (int kt = 0; kt < 4; ++kt) {
        float4 x0 = *(const float4*)(hrow + kt * 32 + quad * 8);
        float4 x1 = *(const float4*)(hrow + kt * 32 + quad * 8 + 4);
        afr[kt] = pack8(x0, x1);
    }
    #pragma unroll
    for (int kt = 0; kt < 4; ++kt) {
        float4 x0 = *(const float4*)(arow + kt * 32 + quad * 8);
        float4 x1 = *(const float4*)(arow + kt * 32 + quad * 8 + 4);
        afr[4 + kt] = pack8(x0, x1);
    }
    {
        bf16x8 a8 = {0, 0, 0, 0, 0, 0, 0, 0};
        if (quad == 0) {
            #pragma unroll
            for (int jj = 0; jj < 8; ++jj) a8[jj] = f2bf(h0[row * INN + jj]);
        } else if (quad == 1) {
            #pragma unroll
            for (int jj = 0; jj < 3; ++jj) a8[jj] = f2bf(h0[row * INN + 8 + jj]);
        }
        afr[8] = a8;
    }
    #pragma unroll
    for (int ct = 0; ct < 4; ++ct) {
        f32x4 acc = {0.f, 0.f, 0.f, 0.f};
        #pragma unroll
        for (int kt = 0; kt < 9; ++kt) {
            bf16x8 bfr = *(const bf16x8*)&BT[(ct * 16 + ln15) * K1S + kt * 32 + quad * 8];
            acc = __builtin_amdgcn_mfma_f32_16x16x32_bf16(afr[kt], bfr, acc, 0, 0, 0);
        }
        int col = c0 + ct * 16 + ln15;
        float b = nb1_l[col];
        #pragma unroll
        for (int r4 = 0; r4 < 4; ++r4) {
            int orow = g * 16 + quad * 4 + r4;
            qb[orow * HD + col] = f2bf(silu_f(acc[r4] + b));
        }
    }
}

// ---------------- node MLP layer 2 + residual (MFMA): h += q @ nw2 + b2 ----------------
__global__ __launch_bounds__(256) void nk2_mfma(
    const short* __restrict__ qb, const float* __restrict__ nw2_l,
    const float* __restrict__ nb2_l, float* __restrict__ h)
{
    __shared__ __align__(16) short BT[128 * 136];  // 34.8 KB
    for (int i = threadIdx.x; i < 128 * 128; i += 256) {
        int c = i >> 7, k = i & 127;
        BT[c * 136 + k] = f2bf(nw2_l[k * HD + c]);
    }
    int wv = threadIdx.x >> 6, lane = threadIdx.x & 63;
    int ln15 = lane & 15, quad = lane >> 4;
    int g = blockIdx.x * 4 + wv;
    __syncthreads();
    if (g >= NG16) return;

    int row = g * 16 + ln15;
    bf16x8 afr[4];
    #pragma unroll
    for (int kt = 0; kt < 4; ++kt)
        afr[kt] = *(const bf16x8*)(qb + row * HD + kt * 32 + quad * 8);

    #pragma unroll
    for (int ct = 0; ct < 8; ++ct) {
        f32x4 acc = {0.f, 0.f, 0.f, 0.f};
        #pragma unroll
        for (int kt = 0; kt < 4; ++kt) {
            bf16x8 bfr = *(const bf16x8*)&BT[(ct * 16 + ln15) * 136 + kt * 32 + quad * 8];
            acc = __builtin_amdgcn_mfma_f32_16x16x32_bf16(afr[kt], bfr, acc, 0, 0, 0);
        }
        int col = ct * 16 + ln15;
        float b = nb2_l[col];
        #pragma unroll
        for (int r4 = 0; r4 < 4; ++r4) {
            int orow = g * 16 + quad * 4 + r4;
            h[orow * HD + col] += acc[r4] + b;
        }
    }
}

extern "C" void kernel_launch(void* const* d_in, const int* in_sizes, int n_in,
                              void* d_out, int out_size, void* d_ws, size_t ws_size,
                              hipStream_t stream)
{
    const float* h0    = (const float*)d_in[0];
    const float* x     = (const float*)d_in[1];
    const int*   ei    = (const int*)d_in[2];
    const float* eattr = (const float*)d_in[3];
    const float* emask = (const float*)d_in[5];
    const float* emb_w = (const float*)d_in[7];
    const float* emb_b = (const float*)d_in[8];
    const float* ew1   = (const float*)d_in[9];
    const float* eb1   = (const float*)d_in[10];
    const float* ew2   = (const float*)d_in[11];
    const float* eb2   = (const float*)d_in[12];
    const float* nw1   = (const float*)d_in[13];
    const float* nb1   = (const float*)d_in[14];
    const float* nw2   = (const float*)d_in[15];
    const float* nb2   = (const float*)d_in[16];

    float* h = (float*)d_out;

    // workspace layout
    short* tb     = (short*)d_ws;                          // NN*HD bf16
    short* ub     = tb + (size_t)NN * HD;                  // NN*HD bf16
    float* agg    = (float*)(ub + (size_t)NN * HD);        // NN*HD fp32
    short* qb     = tb;                                    // alias (t dead by nk1)
    short* mm     = (short*)(agg + (size_t)NN * HD);       // NE*HD bf16
    int*   cnt    = (int*)(mm + (size_t)NE * HD);          // NN
    int*   rowptr = cnt + NN;                              // NN+1
    int*   cursor = rowptr + NN + 1;                       // NN
    int*   eidx   = cursor + NN;                           // NE

    // CSR build (once per launch)
    csr_zero<<<(NN + 255) / 256, 256, 0, stream>>>(cnt);
    csr_hist<<<NE / 256, 256, 0, stream>>>(ei, cnt);
    csr_scan<<<1, 1024, 0, stream>>>(cnt, rowptr, cursor);
    csr_fill<<<NE / 256, 256, 0, stream>>>(ei, cursor, eidx);

    embed_kernel<<<(NN * HD + 255) / 256, 256, 0, stream>>>(h0, emb_w, emb_b, h);

    dim3 gtu((NG16 + 3) / 4, 2);
    dim3 gn1((NG16 + 3) / 4, 2);
    for (int l = 0; l < NL; ++l) {
        tu_mfma<<<gtu, 256, 0, stream>>>(h, ew1 + l * 261 * HD, tb, ub);
        edge_m_kernel<<<1024, 256, 0, stream>>>(tb, ub, x, eattr, emask, ei,
            ew1 + l * 261 * HD, eb1 + l * HD, ew2 + l * HD * HD, eb2 + l * HD, mm);
        agg_gather<<<NN / 4, 256, 0, stream>>>(mm, rowptr, eidx, agg);
        nk1_mfma<<<gn1, 256, 0, stream>>>(h, agg, h0,
            nw1 + l * 267 * HD, nb1 + l * HD, qb);
        nk2_mfma<<<(NG16 + 3) / 4, 256, 0, stream>>>(qb, nw2 + l * HD * HD, nb2 + l * HD, h);
    }
}

// Round 7
// 2424.474 us; speedup vs baseline: 7.0851x; 1.0576x over previous
//
#include <hip/hip_runtime.h>

#define NN 50000
#define NE 800000
#define HD 128
#define INN 11
#define NL 4
#define NG16 3125        // 16-row node groups
#define EGROUPS 12500    // 64-edge groups
#define BTS 132          // LDS K stride (shorts): 66 dwords, gcd(66,32)=2 -> conflict-free
#define K1S 292          // nk1 K stride: 146 dwords, gcd=2 -> conflict-free

typedef __attribute__((ext_vector_type(8))) short bf16x8;
typedef __attribute__((ext_vector_type(4))) float f32x4;

__device__ __forceinline__ float silu_f(float x) { return x / (1.0f + __expf(-x)); }

__device__ __forceinline__ short f2bf(float x) {
    unsigned u = __float_as_uint(x);
    return (short)((u + 0x7FFFu + ((u >> 16) & 1u)) >> 16);
}
__device__ __forceinline__ float bf2f(short s) {
    return __uint_as_float(((unsigned)(unsigned short)s) << 16);
}
__device__ __forceinline__ bf16x8 pack8(float4 a, float4 b) {
    bf16x8 r;
    r[0] = f2bf(a.x); r[1] = f2bf(a.y); r[2] = f2bf(a.z); r[3] = f2bf(a.w);
    r[4] = f2bf(b.x); r[5] = f2bf(b.y); r[6] = f2bf(b.z); r[7] = f2bf(b.w);
    return r;
}

// ---------------- zero agg ----------------
__global__ __launch_bounds__(256) void zero_kernel(float4* __restrict__ p, int n4)
{
    int i = blockIdx.x * 256 + threadIdx.x;
    if (i < n4) p[i] = make_float4(0.f, 0.f, 0.f, 0.f);
}

// ---------------- embedding ----------------
__global__ __launch_bounds__(256) void embed_kernel(
    const float* __restrict__ h0, const float* __restrict__ w,
    const float* __restrict__ b, float* __restrict__ h)
{
    int idx = blockIdx.x * 256 + threadIdx.x;
    if (idx >= NN * HD) return;
    int n = idx >> 7, j = idx & 127;
    float acc = b[j];
    #pragma unroll
    for (int k = 0; k < INN; ++k)
        acc += h0[n * INN + k] * w[k * HD + j];
    h[idx] = acc;
}

// ---------------- CSR build ----------------
__global__ __launch_bounds__(256) void csr_zero(int* __restrict__ cnt)
{
    int i = blockIdx.x * 256 + threadIdx.x;
    if (i < NN) cnt[i] = 0;
}

__global__ __launch_bounds__(256) void csr_hist(const int* __restrict__ ei, int* __restrict__ cnt)
{
    int e = blockIdx.x * 256 + threadIdx.x;
    atomicAdd(&cnt[ei[e]], 1);
}

__global__ __launch_bounds__(1024) void csr_scan(
    const int* __restrict__ cnt, int* __restrict__ rowptr, int* __restrict__ cursor)
{
    __shared__ int part[1024];
    int t = threadIdx.x;
    int base = t * 49;
    int s = 0;
    for (int i = 0; i < 49; ++i) { int j = base + i; if (j < NN) s += cnt[j]; }
    part[t] = s;
    __syncthreads();
    for (int off = 1; off < 1024; off <<= 1) {
        int v = (t >= off) ? part[t - off] : 0;
        __syncthreads();
        part[t] += v;
        __syncthreads();
    }
    int run = (t == 0) ? 0 : part[t - 1];
    for (int i = 0; i < 49; ++i) {
        int j = base + i;
        if (j < NN) { rowptr[j] = run; cursor[j] = run; run += cnt[j]; }
    }
    if (t == 1023) rowptr[NN] = part[1023];
}

__global__ __launch_bounds__(256) void csr_fill(
    const int* __restrict__ ei, int* __restrict__ cursor, int* __restrict__ eidx)
{
    int e = blockIdx.x * 256 + threadIdx.x;
    int r = ei[e];
    int p = atomicAdd(&cursor[r], 1);
    eidx[p] = e;
}

// ---------------- per-edge data, permuted to CSR order (layer-invariant) ----------------
__global__ __launch_bounds__(256) void edge_pre(
    const int* __restrict__ ei, const int* __restrict__ eidx,
    const float* __restrict__ x, const float* __restrict__ eattr,
    const float* __restrict__ emask,
    int2* __restrict__ rc_p, float2* __restrict__ rm_p, float4* __restrict__ ea_p)
{
    int p = blockIdx.x * 256 + threadIdx.x;
    int e = eidx[p];
    int r = ei[e], c = ei[NE + e];
    rc_p[p] = make_int2(r, c);
    float dx = x[3 * r]     - x[3 * c];
    float dy = x[3 * r + 1] - x[3 * c + 1];
    float dz = x[3 * r + 2] - x[3 * c + 2];
    rm_p[p] = make_float2(dx * dx + dy * dy + dz * dz, emask[e]);
    ea_p[p] = ((const float4*)eattr)[e];
}

// ---------------- t|u = h @ ew1 halves (MFMA, bf16 out) ----------------
__global__ __launch_bounds__(256) void tu_mfma(
    const float* __restrict__ h, const float* __restrict__ ew1_l,
    short* __restrict__ tb, short* __restrict__ ub)
{
    __shared__ __align__(16) short BT[128 * BTS];
    const float* wsrc = ew1_l + (blockIdx.y ? 128 * HD : 0);
    short* outp = blockIdx.y ? ub : tb;
    for (int i = threadIdx.x; i < 128 * 128; i += 256) {
        int c = i >> 7, k = i & 127;
        BT[c * BTS + k] = f2bf(wsrc[k * HD + c]);
    }
    int wv = threadIdx.x >> 6, lane = threadIdx.x & 63;
    int ln15 = lane & 15, quad = lane >> 4;
    int g = blockIdx.x * 4 + wv;
    __syncthreads();
    if (g >= NG16) return;

    int row = g * 16 + ln15;
    const float* hrow = h + row * HD;
    bf16x8 afr[4];
    #pragma unroll
    for (int kt = 0; kt < 4; ++kt) {
        float4 x0 = *(const float4*)(hrow + kt * 32 + quad * 8);
        float4 x1 = *(const float4*)(hrow + kt * 32 + quad * 8 + 4);
        afr[kt] = pack8(x0, x1);
    }
    #pragma unroll
    for (int ct = 0; ct < 8; ++ct) {
        f32x4 acc = {0.f, 0.f, 0.f, 0.f};
        #pragma unroll
        for (int kt = 0; kt < 4; ++kt) {
            bf16x8 bfr = *(const bf16x8*)&BT[(ct * 16 + ln15) * BTS + kt * 32 + quad * 8];
            acc = __builtin_amdgcn_mfma_f32_16x16x32_bf16(afr[kt], bfr, acc, 0, 0, 0);
        }
        int col = ct * 16 + ln15;
        #pragma unroll
        for (int r4 = 0; r4 < 4; ++r4) {
            int orow = g * 16 + quad * 4 + r4;
            outp[orow * HD + col] = f2bf(acc[r4]);
        }
    }
}

// ---------------- fused edge model + MFMA + segmented atomic scatter ----------------
__global__ __launch_bounds__(256) void edge_m_kernel(
    const short* __restrict__ tb, const short* __restrict__ ub,
    const int2* __restrict__ rc_p, const float2* __restrict__ rm_p,
    const float4* __restrict__ ea_p,
    const float* __restrict__ ew1_l, const float* __restrict__ eb1_l,
    const float* __restrict__ ew2_l, const float* __restrict__ eb2_l,
    float* __restrict__ agg)
{
    __shared__ __align__(16) short BT[128 * BTS];  // 33792 B
    __shared__ __align__(16) short VA[64 * BTS];   // 16896 B
    __shared__ int    s_r[64];
    __shared__ int    s_c[64];
    __shared__ float  s_rad[64];
    __shared__ float  s_mask[64];
    __shared__ float4 s_ea[64];
    __shared__ float  s_b2[128];

    for (int i = threadIdx.x; i < 128 * 128; i += 256) {
        int k = i >> 7, n = i & 127;
        BT[n * BTS + k] = f2bf(ew2_l[i]);
    }
    if (threadIdx.x < 128) s_b2[threadIdx.x] = eb2_l[threadIdx.x];

    int j  = threadIdx.x & 127;
    int eh = threadIdx.x >> 7;
    float wr  = ew1_l[256 * HD + j];
    float wa0 = ew1_l[257 * HD + j];
    float wa1 = ew1_l[258 * HD + j];
    float wa2 = ew1_l[259 * HD + j];
    float wa3 = ew1_l[260 * HD + j];
    float b1  = eb1_l[j];

    int lane = threadIdx.x & 63;
    int wv   = threadIdx.x >> 6;
    int ln15 = lane & 15;
    int quad = lane >> 4;
    int mbase = wv * 16;

    for (int g = blockIdx.x; g < EGROUPS; g += gridDim.x) {
        __syncthreads();
        if (threadIdx.x < 64) {
            int p = g * 64 + threadIdx.x;
            int2 rc = rc_p[p];
            float2 rm = rm_p[p];
            s_r[threadIdx.x]    = rc.x;
            s_c[threadIdx.x]    = rc.y;
            s_rad[threadIdx.x]  = rm.x;
            s_mask[threadIdx.x] = rm.y;
            s_ea[threadIdx.x]   = ea_p[p];
        }
        __syncthreads();

        #pragma unroll 4
        for (int i = 0; i < 32; ++i) {
            int el = i * 2 + eh;
            float4 ea = s_ea[el];
            float val = bf2f(tb[s_r[el] * HD + j]) + bf2f(ub[s_c[el] * HD + j])
                      + s_rad[el] * wr
                      + ea.x * wa0 + ea.y * wa1 + ea.z * wa2 + ea.w * wa3 + b1;
            VA[el * BTS + j] = f2bf(silu_f(val));
        }
        __syncthreads();

        bf16x8 afr[4];
        #pragma unroll
        for (int kt = 0; kt < 4; ++kt)
            afr[kt] = *(const bf16x8*)&VA[(mbase + ln15) * BTS + kt * 32 + quad * 8];

        int r0 = s_r[mbase + quad * 4 + 0];
        int r1 = s_r[mbase + quad * 4 + 1];
        int r2 = s_r[mbase + quad * 4 + 2];
        int r3 = s_r[mbase + quad * 4 + 3];

        #pragma unroll
        for (int ct = 0; ct < 8; ++ct) {
            f32x4 acc = {0.f, 0.f, 0.f, 0.f};
            #pragma unroll
            for (int kt = 0; kt < 4; ++kt) {
                bf16x8 bfr = *(const bf16x8*)&BT[(ct * 16 + ln15) * BTS + kt * 32 + quad * 8];
                acc = __builtin_amdgcn_mfma_f32_16x16x32_bf16(afr[kt], bfr, acc, 0, 0, 0);
            }
            int col = ct * 16 + ln15;
            float b2c = s_b2[col];
            float m0 = silu_f(acc[0] + b2c) * s_mask[mbase + quad * 4 + 0];
            float m1 = silu_f(acc[1] + b2c) * s_mask[mbase + quad * 4 + 1];
            float m2 = silu_f(acc[2] + b2c) * s_mask[mbase + quad * 4 + 2];
            float m3 = silu_f(acc[3] + b2c) * s_mask[mbase + quad * 4 + 3];
            // run-length segmented flush (rows are CSR-sorted)
            float run = m0;
            int cur = r0;
            if (r1 != cur) { atomicAdd(&agg[cur * HD + col], run); run = 0.f; cur = r1; }
            run += m1;
            if (r2 != cur) { atomicAdd(&agg[cur * HD + col], run); run = 0.f; cur = r2; }
            run += m2;
            if (r3 != cur) { atomicAdd(&agg[cur * HD + col], run); run = 0.f; cur = r3; }
            run += m3;
            atomicAdd(&agg[cur * HD + col], run);
        }
    }
}

// ---------------- node MLP layer 1 (MFMA) ----------------
__global__ __launch_bounds__(256) void nk1_mfma(
    const float* __restrict__ h, const float* __restrict__ agg,
    const float* __restrict__ h0,
    const float* __restrict__ nw1_l, const float* __restrict__ nb1_l,
    short* __restrict__ qb)
{
    __shared__ __align__(16) short BT[64 * K1S];
    int c0 = blockIdx.y * 64;
    for (int i = threadIdx.x; i < 64 * 288; i += 256) {
        int c = i / 288, k = i - c * 288;
        BT[c * K1S + k] = (k < 267) ? f2bf(nw1_l[k * HD + c0 + c]) : (short)0;
    }
    int wv = threadIdx.x >> 6, lane = threadIdx.x & 63;
    int ln15 = lane & 15, quad = lane >> 4;
    int g = blockIdx.x * 4 + wv;
    __syncthreads();
    if (g >= NG16) return;

    int row = g * 16 + ln15;
    const float* hrow = h + row * HD;
    const float* arow = agg + row * HD;
    bf16x8 afr[9];
    #pragma unroll
    for (int kt = 0; kt < 4; ++kt) {
        float4 x0 = *(const float4*)(hrow + kt * 32 + quad * 8);
        float4 x1 = *(const float4*)(hrow + kt * 32 + quad * 8 + 4);
        afr[kt] = pack8(x0, x1);
    }
    #pragma unroll
    for (int kt = 0; kt < 4; ++kt) {
        float4 x0 = *(const float4*)(arow + kt * 32 + quad * 8);
        float4 x1 = *(const float4*)(arow + kt * 32 + quad * 8 + 4);
        afr[4 + kt] = pack8(x0, x1);
    }
    {
        bf16x8 a8 = {0, 0, 0, 0, 0, 0, 0, 0};
        if (quad == 0) {
            #pragma unroll
            for (int jj = 0; jj < 8; ++jj) a8[jj] = f2bf(h0[row * INN + jj]);
        } else if (quad == 1) {
            #pragma unroll
            for (int jj = 0; jj < 3; ++jj) a8[jj] = f2bf(h0[row * INN + 8 + jj]);
        }
        afr[8] = a8;
    }
    #pragma unroll
    for (int ct = 0; ct < 4; ++ct) {
        f32x4 acc = {0.f, 0.f, 0.f, 0.f};
        #pragma unroll
        for (int kt = 0; kt < 9; ++kt) {
            bf16x8 bfr = *(const bf16x8*)&BT[(ct * 16 + ln15) * K1S + kt * 32 + quad * 8];
            acc = __builtin_amdgcn_mfma_f32_16x16x32_bf16(afr[kt], bfr, acc, 0, 0, 0);
        }
        int col = c0 + ct * 16 + ln15;
        float b = nb1_l[col];
        #pragma unroll
        for (int r4 = 0; r4 < 4; ++r4) {
            int orow = g * 16 + quad * 4 + r4;
            qb[orow * HD + col] = f2bf(silu_f(acc[r4] + b));
        }
    }
}

// ---------------- node MLP layer 2 + residual (MFMA) ----------------
__global__ __launch_bounds__(256) void nk2_mfma(
    const short* __restrict__ qb, const float* __restrict__ nw2_l,
    const float* __restrict__ nb2_l, float* __restrict__ h)
{
    __shared__ __align__(16) short BT[128 * BTS];
    for (int i = threadIdx.x; i < 128 * 128; i += 256) {
        int c = i >> 7, k = i & 127;
        BT[c * BTS + k] = f2bf(nw2_l[k * HD + c]);
    }
    int wv = threadIdx.x >> 6, lane = threadIdx.x & 63;
    int ln15 = lane & 15, quad = lane >> 4;
    int g = blockIdx.x * 4 + wv;
    __syncthreads();
    if (g >= NG16) return;

    int row = g * 16 + ln15;
    bf16x8 afr[4];
    #pragma unroll
    for (int kt = 0; kt < 4; ++kt)
        afr[kt] = *(const bf16x8*)(qb + row * HD + kt * 32 + quad * 8);

    #pragma unroll
    for (int ct = 0; ct < 8; ++ct) {
        f32x4 acc = {0.f, 0.f, 0.f, 0.f};
        #pragma unroll
        for (int kt = 0; kt < 4; ++kt) {
            bf16x8 bfr = *(const bf16x8*)&BT[(ct * 16 + ln15) * BTS + kt * 32 + quad * 8];
            acc = __builtin_amdgcn_mfma_f32_16x16x32_bf16(afr[kt], bfr, acc, 0, 0, 0);
        }
        int col = ct * 16 + ln15;
        float b = nb2_l[col];
        #pragma unroll
        for (int r4 = 0; r4 < 4; ++r4) {
            int orow = g * 16 + quad * 4 + r4;
            h[orow * HD + col] += acc[r4] + b;
        }
    }
}

extern "C" void kernel_launch(void* const* d_in, const int* in_sizes, int n_in,
                              void* d_out, int out_size, void* d_ws, size_t ws_size,
                              hipStream_t stream)
{
    const float* h0    = (const float*)d_in[0];
    const float* x     = (const float*)d_in[1];
    const int*   ei    = (const int*)d_in[2];
    const float* eattr = (const float*)d_in[3];
    const float* emask = (const float*)d_in[5];
    const float* emb_w = (const float*)d_in[7];
    const float* emb_b = (const float*)d_in[8];
    const float* ew1   = (const float*)d_in[9];
    const float* eb1   = (const float*)d_in[10];
    const float* ew2   = (const float*)d_in[11];
    const float* eb2   = (const float*)d_in[12];
    const float* nw1   = (const float*)d_in[13];
    const float* nb1   = (const float*)d_in[14];
    const float* nw2   = (const float*)d_in[15];
    const float* nb2   = (const float*)d_in[16];

    float* h = (float*)d_out;

    // workspace layout (~80.6 MB total; d_ws is 256 MiB)
    short*  tb     = (short*)d_ws;                         // NN*HD bf16  12.8 MB
    short*  ub     = tb + (size_t)NN * HD;                 // NN*HD bf16  12.8 MB
    float*  agg    = (float*)(ub + (size_t)NN * HD);       // NN*HD fp32  25.6 MB
    short*  qb     = tb;                                   // alias (tb dead by nk1)
    int*    cnt    = (int*)(agg + (size_t)NN * HD);        // NN
    int*    rowptr = cnt + NN;                             // NN+1
    int*    cursor = rowptr + NN + 1;                      // NN
    int*    eidx   = cursor + NN;                          // NE          3.2 MB
    int2*   rc_p   = (int2*)(eidx + NE);                   // NE int2     6.4 MB
    float2* rm_p   = (float2*)(rc_p + NE);                 // NE float2   6.4 MB
    float4* ea_p   = (float4*)(rm_p + NE);                 // NE float4  12.8 MB

    // CSR build + permuted edge data (once per launch)
    csr_zero<<<(NN + 255) / 256, 256, 0, stream>>>(cnt);
    csr_hist<<<NE / 256, 256, 0, stream>>>(ei, cnt);
    csr_scan<<<1, 1024, 0, stream>>>(cnt, rowptr, cursor);
    csr_fill<<<NE / 256, 256, 0, stream>>>(ei, cursor, eidx);
    edge_pre<<<NE / 256, 256, 0, stream>>>(ei, eidx, x, eattr, emask, rc_p, rm_p, ea_p);

    embed_kernel<<<(NN * HD + 255) / 256, 256, 0, stream>>>(h0, emb_w, emb_b, h);

    dim3 gtu((NG16 + 3) / 4, 2);
    dim3 gn1((NG16 + 3) / 4, 2);
    for (int l = 0; l < NL; ++l) {
        tu_mfma<<<gtu, 256, 0, stream>>>(h, ew1 + l * 261 * HD, tb, ub);
        zero_kernel<<<(NN * HD / 4 + 255) / 256, 256, 0, stream>>>((float4*)agg, NN * HD / 4);
        edge_m_kernel<<<768, 256, 0, stream>>>(tb, ub, rc_p, rm_p, ea_p,
            ew1 + l * 261 * HD, eb1 + l * HD, ew2 + l * HD * HD, eb2 + l * HD, agg);
        nk1_mfma<<<gn1, 256, 0, stream>>>(h, agg, h0,
            nw1 + l * 267 * HD, nb1 + l * HD, qb);
        nk2_mfma<<<(NG16 + 3) / 4, 256, 0, stream>>>(qb, nw2 + l * HD * HD, nb2 + l * HD, h);
    }
}

// Round 8
// 1939.672 us; speedup vs baseline: 8.8560x; 1.2499x over previous
//
#include <hip/hip_runtime.h>

#define NN 50000
#define NE 800000
#define HD 128
#define INN 11
#define NL 4
#define NG16 3125        // 16-row node groups
#define EGROUPS 12500    // 64-edge groups
#define BTS 132          // LDS K stride (shorts): 66 dwords, gcd(66,32)=2 -> conflict-free
#define K1S 292          // nk1 K stride: 146 dwords, gcd(146,32)=2 -> conflict-free

typedef __attribute__((ext_vector_type(8))) short bf16x8;
typedef __attribute__((ext_vector_type(4))) float f32x4;

__device__ __forceinline__ float silu_f(float x) { return x / (1.0f + __expf(-x)); }

__device__ __forceinline__ short f2bf(float x) {
    unsigned u = __float_as_uint(x);
    return (short)((u + 0x7FFFu + ((u >> 16) & 1u)) >> 16);
}
__device__ __forceinline__ unsigned f2bf2u(float lo, float hi) {
    unsigned a = __float_as_uint(lo), b = __float_as_uint(hi);
    a = (a + 0x7FFFu + ((a >> 16) & 1u)) >> 16;
    b = (b + 0x7FFFu + ((b >> 16) & 1u)) & 0xFFFF0000u;
    return a | b;
}
__device__ __forceinline__ float bf2f(short s) {
    return __uint_as_float(((unsigned)(unsigned short)s) << 16);
}
__device__ __forceinline__ bf16x8 pack8(float4 a, float4 b) {
    bf16x8 r;
    r[0] = f2bf(a.x); r[1] = f2bf(a.y); r[2] = f2bf(a.z); r[3] = f2bf(a.w);
    r[4] = f2bf(b.x); r[5] = f2bf(b.y); r[6] = f2bf(b.z); r[7] = f2bf(b.w);
    return r;
}

// ---------------- zero agg ----------------
__global__ __launch_bounds__(256) void zero_kernel(float4* __restrict__ p, int n4)
{
    int i = blockIdx.x * 256 + threadIdx.x;
    if (i < n4) p[i] = make_float4(0.f, 0.f, 0.f, 0.f);
}

// ---------------- embedding ----------------
__global__ __launch_bounds__(256) void embed_kernel(
    const float* __restrict__ h0, const float* __restrict__ w,
    const float* __restrict__ b, float* __restrict__ h)
{
    int idx = blockIdx.x * 256 + threadIdx.x;
    if (idx >= NN * HD) return;
    int n = idx >> 7, j = idx & 127;
    float acc = b[j];
    #pragma unroll
    for (int k = 0; k < INN; ++k)
        acc += h0[n * INN + k] * w[k * HD + j];
    h[idx] = acc;
}

// ---------------- CSR build ----------------
__global__ __launch_bounds__(256) void csr_zero(int* __restrict__ cnt)
{
    int i = blockIdx.x * 256 + threadIdx.x;
    if (i < NN) cnt[i] = 0;
}

__global__ __launch_bounds__(256) void csr_hist(const int* __restrict__ ei, int* __restrict__ cnt)
{
    int e = blockIdx.x * 256 + threadIdx.x;
    atomicAdd(&cnt[ei[e]], 1);
}

__global__ __launch_bounds__(1024) void csr_scan(
    const int* __restrict__ cnt, int* __restrict__ rowptr, int* __restrict__ cursor)
{
    __shared__ int part[1024];
    int t = threadIdx.x;
    int base = t * 49;
    int s = 0;
    for (int i = 0; i < 49; ++i) { int j = base + i; if (j < NN) s += cnt[j]; }
    part[t] = s;
    __syncthreads();
    for (int off = 1; off < 1024; off <<= 1) {
        int v = (t >= off) ? part[t - off] : 0;
        __syncthreads();
        part[t] += v;
        __syncthreads();
    }
    int run = (t == 0) ? 0 : part[t - 1];
    for (int i = 0; i < 49; ++i) {
        int j = base + i;
        if (j < NN) { rowptr[j] = run; cursor[j] = run; run += cnt[j]; }
    }
    if (t == 1023) rowptr[NN] = part[1023];
}

__global__ __launch_bounds__(256) void csr_fill(
    const int* __restrict__ ei, int* __restrict__ cursor, int* __restrict__ eidx)
{
    int e = blockIdx.x * 256 + threadIdx.x;
    int r = ei[e];
    int p = atomicAdd(&cursor[r], 1);
    eidx[p] = e;
}

// ---------------- per-edge data, permuted to CSR order ----------------
__global__ __launch_bounds__(256) void edge_pre(
    const int* __restrict__ ei, const int* __restrict__ eidx,
    const float* __restrict__ x, const float* __restrict__ eattr,
    const float* __restrict__ emask,
    int2* __restrict__ rc_p, float2* __restrict__ rm_p, float4* __restrict__ ea_p)
{
    int p = blockIdx.x * 256 + threadIdx.x;
    int e = eidx[p];
    int r = ei[e], c = ei[NE + e];
    rc_p[p] = make_int2(r, c);
    float dx = x[3 * r]     - x[3 * c];
    float dy = x[3 * r + 1] - x[3 * c + 1];
    float dz = x[3 * r + 2] - x[3 * c + 2];
    rm_p[p] = make_float2(dx * dx + dy * dy + dz * dz, emask[e]);
    ea_p[p] = ((const float4*)eattr)[e];
}

// ---------------- t|u = h @ ew1 halves (persistent MFMA, bf16 out) ----------------
__global__ __launch_bounds__(512) void tu_mfma(
    const float* __restrict__ h, const float* __restrict__ ew1_l,
    short* __restrict__ tb, short* __restrict__ ub)
{
    __shared__ __align__(16) short BT[128 * BTS];
    const float* wsrc = ew1_l + (blockIdx.y ? 128 * HD : 0);
    short* outp = blockIdx.y ? ub : tb;
    for (int i = threadIdx.x; i < 128 * 128; i += 512) {
        int c = i >> 7, k = i & 127;
        BT[c * BTS + k] = f2bf(wsrc[k * HD + c]);
    }
    int wv = threadIdx.x >> 6, lane = threadIdx.x & 63;
    int ln15 = lane & 15, quad = lane >> 4;
    __syncthreads();

    for (int g = blockIdx.x * 8 + wv; g < NG16; g += gridDim.x * 8) {
        int row = g * 16 + ln15;
        const float* hrow = h + row * HD;
        bf16x8 afr[4];
        #pragma unroll
        for (int kt = 0; kt < 4; ++kt) {
            float4 x0 = *(const float4*)(hrow + kt * 32 + quad * 8);
            float4 x1 = *(const float4*)(hrow + kt * 32 + quad * 8 + 4);
            afr[kt] = pack8(x0, x1);
        }
        #pragma unroll
        for (int ct = 0; ct < 8; ++ct) {
            f32x4 acc = {0.f, 0.f, 0.f, 0.f};
            #pragma unroll
            for (int kt = 0; kt < 4; ++kt) {
                bf16x8 bfr = *(const bf16x8*)&BT[(ct * 16 + ln15) * BTS + kt * 32 + quad * 8];
                acc = __builtin_amdgcn_mfma_f32_16x16x32_bf16(afr[kt], bfr, acc, 0, 0, 0);
            }
            int col = ct * 16 + ln15;
            #pragma unroll
            for (int r4 = 0; r4 < 4; ++r4) {
                int orow = g * 16 + quad * 4 + r4;
                outp[orow * HD + col] = f2bf(acc[r4]);
            }
        }
    }
}

// ---------------- fused edge model + MFMA + segmented atomic scatter ----------------
// v-phase: thread <-> (col-pair cp, edge-quarter eq); dword gathers, no staging phase.
__global__ __launch_bounds__(256) void edge_m_kernel(
    const short* __restrict__ tb, const short* __restrict__ ub,
    const int2* __restrict__ rc_p, const float2* __restrict__ rm_p,
    const float4* __restrict__ ea_p,
    const float* __restrict__ ew1_l, const float* __restrict__ eb1_l,
    const float* __restrict__ ew2_l, const float* __restrict__ eb2_l,
    float* __restrict__ agg)
{
    __shared__ __align__(16) short BT[128 * BTS];  // 33792 B
    __shared__ __align__(16) short VA[64 * BTS];   // 16896 B
    __shared__ float s_b2[128];

    for (int i = threadIdx.x; i < 128 * 128; i += 256) {
        int k = i >> 7, n = i & 127;
        BT[n * BTS + k] = f2bf(ew2_l[i]);
    }
    if (threadIdx.x < 128) s_b2[threadIdx.x] = eb2_l[threadIdx.x];

    // per-thread column-pair constants (cols 2cp, 2cp+1)
    int cp = threadIdx.x & 63;
    int eq = threadIdx.x >> 6;
    int c0 = cp * 2;
    float wr0  = ew1_l[256 * HD + c0],     wr1  = ew1_l[256 * HD + c0 + 1];
    float wa00 = ew1_l[257 * HD + c0],     wa01 = ew1_l[257 * HD + c0 + 1];
    float wa10 = ew1_l[258 * HD + c0],     wa11 = ew1_l[258 * HD + c0 + 1];
    float wa20 = ew1_l[259 * HD + c0],     wa21 = ew1_l[259 * HD + c0 + 1];
    float wa30 = ew1_l[260 * HD + c0],     wa31 = ew1_l[260 * HD + c0 + 1];
    float b10  = eb1_l[c0],                b11  = eb1_l[c0 + 1];

    int lane = threadIdx.x & 63;
    int wv   = threadIdx.x >> 6;
    int ln15 = lane & 15;
    int quad = lane >> 4;
    int mbase = wv * 16;
    __syncthreads();

    for (int g = blockIdx.x; g < EGROUPS; g += gridDim.x) {
        // ---- v-phase: this thread computes cols {c0,c0+1} for edges eq*16..eq*16+15
        const unsigned* tb32 = (const unsigned*)tb;
        const unsigned* ub32 = (const unsigned*)ub;
        #pragma unroll 4
        for (int i = 0; i < 16; ++i) {
            int el = eq * 16 + i;
            int p  = g * 64 + el;
            int2   rc = rc_p[p];
            float2 rm = rm_p[p];
            float4 ea = ea_p[p];
            unsigned tw = tb32[rc.x * 64 + cp];
            unsigned uw = ub32[rc.y * 64 + cp];
            float t0 = __uint_as_float(tw << 16);
            float t1 = __uint_as_float(tw & 0xFFFF0000u);
            float u0 = __uint_as_float(uw << 16);
            float u1 = __uint_as_float(uw & 0xFFFF0000u);
            float base0 = rm.x * wr0 + ea.x * wa00 + ea.y * wa10 + ea.z * wa20 + ea.w * wa30 + b10;
            float base1 = rm.x * wr1 + ea.x * wa01 + ea.y * wa11 + ea.z * wa21 + ea.w * wa31 + b11;
            float v0 = silu_f(t0 + u0 + base0);
            float v1 = silu_f(t1 + u1 + base1);
            *(unsigned*)&VA[el * BTS + c0] = f2bf2u(v0, v1);
        }

        // epilogue edge metadata (hoisted: in flight across the barrier)
        int em0 = g * 64 + mbase + quad * 4;
        int   r0 = rc_p[em0 + 0].x, r1 = rc_p[em0 + 1].x;
        int   r2 = rc_p[em0 + 2].x, r3 = rc_p[em0 + 3].x;
        float mk0 = rm_p[em0 + 0].y, mk1 = rm_p[em0 + 1].y;
        float mk2 = rm_p[em0 + 2].y, mk3 = rm_p[em0 + 3].y;

        __syncthreads();   // VA ready

        bf16x8 afr[4];
        #pragma unroll
        for (int kt = 0; kt < 4; ++kt)
            afr[kt] = *(const bf16x8*)&VA[(mbase + ln15) * BTS + kt * 32 + quad * 8];

        __syncthreads();   // all VA reads done; next v-phase may overwrite

        #pragma unroll
        for (int ct = 0; ct < 8; ++ct) {
            f32x4 acc = {0.f, 0.f, 0.f, 0.f};
            #pragma unroll
            for (int kt = 0; kt < 4; ++kt) {
                bf16x8 bfr = *(const bf16x8*)&BT[(ct * 16 + ln15) * BTS + kt * 32 + quad * 8];
                acc = __builtin_amdgcn_mfma_f32_16x16x32_bf16(afr[kt], bfr, acc, 0, 0, 0);
            }
            int col = ct * 16 + ln15;
            float b2c = s_b2[col];
            float m0 = silu_f(acc[0] + b2c) * mk0;
            float m1 = silu_f(acc[1] + b2c) * mk1;
            float m2 = silu_f(acc[2] + b2c) * mk2;
            float m3 = silu_f(acc[3] + b2c) * mk3;
            // run-length segmented flush (rows CSR-sorted)
            float run = m0;
            int cur = r0;
            if (r1 != cur) { atomicAdd(&agg[cur * HD + col], run); run = 0.f; cur = r1; }
            run += m1;
            if (r2 != cur) { atomicAdd(&agg[cur * HD + col], run); run = 0.f; cur = r2; }
            run += m2;
            if (r3 != cur) { atomicAdd(&agg[cur * HD + col], run); run = 0.f; cur = r3; }
            run += m3;
            atomicAdd(&agg[cur * HD + col], run);
        }
    }
}

// ---------------- node MLP layer 1 (persistent MFMA) ----------------
__global__ __launch_bounds__(512) void nk1_mfma(
    const float* __restrict__ h, const float* __restrict__ agg,
    const float* __restrict__ h0,
    const float* __restrict__ nw1_l, const float* __restrict__ nb1_l,
    short* __restrict__ qb)
{
    __shared__ __align__(16) short BT[64 * K1S];
    int c0 = blockIdx.y * 64;
    for (int i = threadIdx.x; i < 64 * 288; i += 512) {
        int c = i / 288, k = i - c * 288;
        BT[c * K1S + k] = (k < 267) ? f2bf(nw1_l[k * HD + c0 + c]) : (short)0;
    }
    int wv = threadIdx.x >> 6, lane = threadIdx.x & 63;
    int ln15 = lane & 15, quad = lane >> 4;
    __syncthreads();

    for (int g = blockIdx.x * 8 + wv; g < NG16; g += gridDim.x * 8) {
        int row = g * 16 + ln15;
        const float* hrow = h + row * HD;
        const float* arow = agg + row * HD;
        bf16x8 afr[9];
        #pragma unroll
        for (int kt = 0; kt < 4; ++kt) {
            float4 x0 = *(const float4*)(hrow + kt * 32 + quad * 8);
            float4 x1 = *(const float4*)(hrow + kt * 32 + quad * 8 + 4);
            afr[kt] = pack8(x0, x1);
        }
        #pragma unroll
        for (int kt = 0; kt < 4; ++kt) {
            float4 x0 = *(const float4*)(arow + kt * 32 + quad * 8);
            float4 x1 = *(const float4*)(arow + kt * 32 + quad * 8 + 4);
            afr[4 + kt] = pack8(x0, x1);
        }
        {
            bf16x8 a8 = {0, 0, 0, 0, 0, 0, 0, 0};
            if (quad == 0) {
                #pragma unroll
                for (int jj = 0; jj < 8; ++jj) a8[jj] = f2bf(h0[row * INN + jj]);
            } else if (quad == 1) {
                #pragma unroll
                for (int jj = 0; jj < 3; ++jj) a8[jj] = f2bf(h0[row * INN + 8 + jj]);
            }
            afr[8] = a8;
        }
        #pragma unroll
        for (int ct = 0; ct < 4; ++ct) {
            f32x4 acc = {0.f, 0.f, 0.f, 0.f};
            #pragma unroll
            for (int kt = 0; kt < 9; ++kt) {
                bf16x8 bfr = *(const bf16x8*)&BT[(ct * 16 + ln15) * K1S + kt * 32 + quad * 8];
                acc = __builtin_amdgcn_mfma_f32_16x16x32_bf16(afr[kt], bfr, acc, 0, 0, 0);
            }
            int col = c0 + ct * 16 + ln15;
            float b = nb1_l[col];
            #pragma unroll
            for (int r4 = 0; r4 < 4; ++r4) {
                int orow = g * 16 + quad * 4 + r4;
                qb[orow * HD + col] = f2bf(silu_f(acc[r4] + b));
            }
        }
    }
}

// ---------------- node MLP layer 2 + residual (persistent MFMA) ----------------
__global__ __launch_bounds__(512) void nk2_mfma(
    const short* __restrict__ qb, const float* __restrict__ nw2_l,
    const float* __restrict__ nb2_l, float* __restrict__ h)
{
    __shared__ __align__(16) short BT[128 * BTS];
    for (int i = threadIdx.x; i < 128 * 128; i += 512) {
        int c = i >> 7, k = i & 127;
        BT[c * BTS + k] = f2bf(nw2_l[k * HD + c]);
    }
    int wv = threadIdx.x >> 6, lane = threadIdx.x & 63;
    int ln15 = lane & 15, quad = lane >> 4;
    __syncthreads();

    for (int g = blockIdx.x * 8 + wv; g < NG16; g += gridDim.x * 8) {
        int row = g * 16 + ln15;
        bf16x8 afr[4];
        #pragma unroll
        for (int kt = 0; kt < 4; ++kt)
            afr[kt] = *(const bf16x8*)(qb + row * HD + kt * 32 + quad * 8);

        #pragma unroll
        for (int ct = 0; ct < 8; ++ct) {
            f32x4 acc = {0.f, 0.f, 0.f, 0.f};
            #pragma unroll
            for (int kt = 0; kt < 4; ++kt) {
                bf16x8 bfr = *(const bf16x8*)&BT[(ct * 16 + ln15) * BTS + kt * 32 + quad * 8];
                acc = __builtin_amdgcn_mfma_f32_16x16x32_bf16(afr[kt], bfr, acc, 0, 0, 0);
            }
            int col = ct * 16 + ln15;
            float b = nb2_l[col];
            #pragma unroll
            for (int r4 = 0; r4 < 4; ++r4) {
                int orow = g * 16 + quad * 4 + r4;
                h[orow * HD + col] += acc[r4] + b;
            }
        }
    }
}

extern "C" void kernel_launch(void* const* d_in, const int* in_sizes, int n_in,
                              void* d_out, int out_size, void* d_ws, size_t ws_size,
                              hipStream_t stream)
{
    const float* h0    = (const float*)d_in[0];
    const float* x     = (const float*)d_in[1];
    const int*   ei    = (const int*)d_in[2];
    const float* eattr = (const float*)d_in[3];
    const float* emask = (const float*)d_in[5];
    const float* emb_w = (const float*)d_in[7];
    const float* emb_b = (const float*)d_in[8];
    const float* ew1   = (const float*)d_in[9];
    const float* eb1   = (const float*)d_in[10];
    const float* ew2   = (const float*)d_in[11];
    const float* eb2   = (const float*)d_in[12];
    const float* nw1   = (const float*)d_in[13];
    const float* nb1   = (const float*)d_in[14];
    const float* nw2   = (const float*)d_in[15];
    const float* nb2   = (const float*)d_in[16];

    float* h = (float*)d_out;

    // workspace layout (~80.6 MB; d_ws >= 256 MiB)
    short*  tb     = (short*)d_ws;                         // NN*HD bf16
    short*  ub     = tb + (size_t)NN * HD;                 // NN*HD bf16
    float*  agg    = (float*)(ub + (size_t)NN * HD);       // NN*HD fp32
    short*  qb     = tb;                                   // alias (tb dead by nk1)
    int*    cnt    = (int*)(agg + (size_t)NN * HD);        // NN
    int*    rowptr = cnt + NN;                             // NN+1
    int*    cursor = rowptr + NN + 1;                      // NN
    int*    eidx   = cursor + NN;                          // NE
    int2*   rc_p   = (int2*)(eidx + NE);                   // NE int2
    float2* rm_p   = (float2*)(rc_p + NE);                 // NE float2
    float4* ea_p   = (float4*)(rm_p + NE);                 // NE float4

    csr_zero<<<(NN + 255) / 256, 256, 0, stream>>>(cnt);
    csr_hist<<<NE / 256, 256, 0, stream>>>(ei, cnt);
    csr_scan<<<1, 1024, 0, stream>>>(cnt, rowptr, cursor);
    csr_fill<<<NE / 256, 256, 0, stream>>>(ei, cursor, eidx);
    edge_pre<<<NE / 256, 256, 0, stream>>>(ei, eidx, x, eattr, emask, rc_p, rm_p, ea_p);

    embed_kernel<<<(NN * HD + 255) / 256, 256, 0, stream>>>(h0, emb_w, emb_b, h);

    dim3 gtu(128, 2);
    dim3 gn1(128, 2);
    for (int l = 0; l < NL; ++l) {
        tu_mfma<<<gtu, 512, 0, stream>>>(h, ew1 + l * 261 * HD, tb, ub);
        zero_kernel<<<(NN * HD / 4 + 255) / 256, 256, 0, stream>>>((float4*)agg, NN * HD / 4);
        edge_m_kernel<<<768, 256, 0, stream>>>(tb, ub, rc_p, rm_p, ea_p,
            ew1 + l * 261 * HD, eb1 + l * HD, ew2 + l * HD * HD, eb2 + l * HD, agg);
        nk1_mfma<<<gn1, 512, 0, stream>>>(h, agg, h0,
            nw1 + l * 267 * HD, nb1 + l * HD, qb);
        nk2_mfma<<<128, 512, 0, stream>>>(qb, nw2 + l * HD * HD, nb2 + l * HD, h);
    }
}

// Round 9
// 1902.168 us; speedup vs baseline: 9.0306x; 1.0197x over previous
//
#include <hip/hip_runtime.h>

#define NN 50000
#define NE 800000
#define HD 128
#define INN 11
#define NL 4
#define NG16 3125        // 16-row node groups
#define EW16 50000       // 16-edge wave-tasks (NE/16)
#define BTS 132          // LDS K stride (shorts): 66 dwords, gcd(66,32)=2 -> conflict-free
#define K1S 292          // nk1 K stride: 146 dwords, gcd(146,32)=2 -> conflict-free

typedef __attribute__((ext_vector_type(8))) short bf16x8;
typedef __attribute__((ext_vector_type(4))) float f32x4;

__device__ __forceinline__ float silu_f(float x) { return x / (1.0f + __expf(-x)); }

__device__ __forceinline__ short f2bf(float x) {
    unsigned u = __float_as_uint(x);
    return (short)((u + 0x7FFFu + ((u >> 16) & 1u)) >> 16);
}
__device__ __forceinline__ unsigned f2bf2u(float lo, float hi) {
    unsigned a = __float_as_uint(lo), b = __float_as_uint(hi);
    a = (a + 0x7FFFu + ((a >> 16) & 1u)) >> 16;
    b = (b + 0x7FFFu + ((b >> 16) & 1u)) & 0xFFFF0000u;
    return a | b;
}
__device__ __forceinline__ bf16x8 pack8(float4 a, float4 b) {
    bf16x8 r;
    r[0] = f2bf(a.x); r[1] = f2bf(a.y); r[2] = f2bf(a.z); r[3] = f2bf(a.w);
    r[4] = f2bf(b.x); r[5] = f2bf(b.y); r[6] = f2bf(b.z); r[7] = f2bf(b.w);
    return r;
}

// ---------------- zero agg ----------------
__global__ __launch_bounds__(256) void zero_kernel(float4* __restrict__ p, int n4)
{
    int i = blockIdx.x * 256 + threadIdx.x;
    if (i < n4) p[i] = make_float4(0.f, 0.f, 0.f, 0.f);
}

// ---------------- embedding ----------------
__global__ __launch_bounds__(256) void embed_kernel(
    const float* __restrict__ h0, const float* __restrict__ w,
    const float* __restrict__ b, float* __restrict__ h)
{
    int idx = blockIdx.x * 256 + threadIdx.x;
    if (idx >= NN * HD) return;
    int n = idx >> 7, j = idx & 127;
    float acc = b[j];
    #pragma unroll
    for (int k = 0; k < INN; ++k)
        acc += h0[n * INN + k] * w[k * HD + j];
    h[idx] = acc;
}

// ---------------- CSR build ----------------
__global__ __launch_bounds__(256) void csr_zero(int* __restrict__ cnt)
{
    int i = blockIdx.x * 256 + threadIdx.x;
    if (i < NN) cnt[i] = 0;
}

__global__ __launch_bounds__(256) void csr_hist(const int* __restrict__ ei, int* __restrict__ cnt)
{
    int e = blockIdx.x * 256 + threadIdx.x;
    atomicAdd(&cnt[ei[e]], 1);
}

__global__ __launch_bounds__(1024) void csr_scan(
    const int* __restrict__ cnt, int* __restrict__ rowptr, int* __restrict__ cursor)
{
    __shared__ int part[1024];
    int t = threadIdx.x;
    int base = t * 49;
    int s = 0;
    for (int i = 0; i < 49; ++i) { int j = base + i; if (j < NN) s += cnt[j]; }
    part[t] = s;
    __syncthreads();
    for (int off = 1; off < 1024; off <<= 1) {
        int v = (t >= off) ? part[t - off] : 0;
        __syncthreads();
        part[t] += v;
        __syncthreads();
    }
    int run = (t == 0) ? 0 : part[t - 1];
    for (int i = 0; i < 49; ++i) {
        int j = base + i;
        if (j < NN) { rowptr[j] = run; cursor[j] = run; run += cnt[j]; }
    }
    if (t == 1023) rowptr[NN] = part[1023];
}

__global__ __launch_bounds__(256) void csr_fill(
    const int* __restrict__ ei, int* __restrict__ cursor, int* __restrict__ eidx)
{
    int e = blockIdx.x * 256 + threadIdx.x;
    int r = ei[e];
    int p = atomicAdd(&cursor[r], 1);
    eidx[p] = e;
}

// ---------------- per-edge data, permuted to CSR order; rc pre-scaled by 64 ----------------
__global__ __launch_bounds__(256) void edge_pre(
    const int* __restrict__ ei, const int* __restrict__ eidx,
    const float* __restrict__ x, const float* __restrict__ eattr,
    const float* __restrict__ emask,
    int2* __restrict__ rc_p, float2* __restrict__ rm_p, float4* __restrict__ ea_p)
{
    int p = blockIdx.x * 256 + threadIdx.x;
    int e = eidx[p];
    int r = ei[e], c = ei[NE + e];
    rc_p[p] = make_int2(r * 64, c * 64);   // dword offsets into tb/ub
    float dx = x[3 * r]     - x[3 * c];
    float dy = x[3 * r + 1] - x[3 * c + 1];
    float dz = x[3 * r + 2] - x[3 * c + 2];
    rm_p[p] = make_float2(dx * dx + dy * dy + dz * dz, emask[e]);
    ea_p[p] = ((const float4*)eattr)[e];
}

// ---------------- t|u = h @ ew1 halves (persistent MFMA, bf16 out) ----------------
__global__ __launch_bounds__(512) void tu_mfma(
    const float* __restrict__ h, const float* __restrict__ ew1_l,
    short* __restrict__ tb, short* __restrict__ ub)
{
    __shared__ __align__(16) short BT[128 * BTS];
    const float* wsrc = ew1_l + (blockIdx.y ? 128 * HD : 0);
    short* outp = blockIdx.y ? ub : tb;
    for (int i = threadIdx.x; i < 128 * 128; i += 512) {
        int c = i >> 7, k = i & 127;
        BT[c * BTS + k] = f2bf(wsrc[k * HD + c]);
    }
    int wv = threadIdx.x >> 6, lane = threadIdx.x & 63;
    int ln15 = lane & 15, quad = lane >> 4;
    __syncthreads();

    for (int g = blockIdx.x * 8 + wv; g < NG16; g += gridDim.x * 8) {
        int row = g * 16 + ln15;
        const float* hrow = h + row * HD;
        bf16x8 afr[4];
        #pragma unroll
        for (int kt = 0; kt < 4; ++kt) {
            float4 x0 = *(const float4*)(hrow + kt * 32 + quad * 8);
            float4 x1 = *(const float4*)(hrow + kt * 32 + quad * 8 + 4);
            afr[kt] = pack8(x0, x1);
        }
        #pragma unroll
        for (int ct = 0; ct < 8; ++ct) {
            f32x4 acc = {0.f, 0.f, 0.f, 0.f};
            #pragma unroll
            for (int kt = 0; kt < 4; ++kt) {
                bf16x8 bfr = *(const bf16x8*)&BT[(ct * 16 + ln15) * BTS + kt * 32 + quad * 8];
                acc = __builtin_amdgcn_mfma_f32_16x16x32_bf16(afr[kt], bfr, acc, 0, 0, 0);
            }
            int col = ct * 16 + ln15;
            #pragma unroll
            for (int r4 = 0; r4 < 4; ++r4) {
                int orow = g * 16 + quad * 4 + r4;
                outp[orow * HD + col] = f2bf(acc[r4]);
            }
        }
    }
}

// ---------------- wave-autonomous fused edge model + MFMA + segmented scatter ----------------
// Each wave owns 16 edges: v-phase (lane = col-pair) -> private VA tile -> MFMA -> atomics.
// No in-loop barriers: same-wave DS ops are processed in order.
__global__ __launch_bounds__(256) void edge_m_kernel(
    const short* __restrict__ tb, const short* __restrict__ ub,
    const int2* __restrict__ rc_p, const float2* __restrict__ rm_p,
    const float4* __restrict__ ea_p,
    const float* __restrict__ ew1_l, const float* __restrict__ eb1_l,
    const float* __restrict__ ew2_l, const float* __restrict__ eb2_l,
    float* __restrict__ agg)
{
    __shared__ __align__(16) short BT[128 * BTS];     // 33792 B
    __shared__ __align__(16) short VA[4][16 * BTS];   // 4 x 4224 B (per-wave private)
    __shared__ float s_b2[128];

    for (int i = threadIdx.x; i < 128 * 128; i += 256) {
        int k = i >> 7, n = i & 127;
        BT[n * BTS + k] = f2bf(ew2_l[i]);
    }
    if (threadIdx.x < 128) s_b2[threadIdx.x] = eb2_l[threadIdx.x];

    // per-thread column-pair constants (cols 2cp, 2cp+1)
    int cp = threadIdx.x & 63;
    int c0 = cp * 2;
    float wr0  = ew1_l[256 * HD + c0],     wr1  = ew1_l[256 * HD + c0 + 1];
    float wa00 = ew1_l[257 * HD + c0],     wa01 = ew1_l[257 * HD + c0 + 1];
    float wa10 = ew1_l[258 * HD + c0],     wa11 = ew1_l[258 * HD + c0 + 1];
    float wa20 = ew1_l[259 * HD + c0],     wa21 = ew1_l[259 * HD + c0 + 1];
    float wa30 = ew1_l[260 * HD + c0],     wa31 = ew1_l[260 * HD + c0 + 1];
    float b10  = eb1_l[c0],                b11  = eb1_l[c0 + 1];

    int lane = threadIdx.x & 63;
    int wv   = threadIdx.x >> 6;
    int ln15 = lane & 15;
    int quad = lane >> 4;
    short* VAw = &VA[wv][0];
    const unsigned* tb32 = (const unsigned*)tb;
    const unsigned* ub32 = (const unsigned*)ub;
    __syncthreads();   // BT ready

    for (int gw = blockIdx.x * 4 + wv; gw < EW16; gw += gridDim.x * 4) {
        // ---- v-phase: 16 edges x cols {c0,c0+1}
        #pragma unroll 8
        for (int i = 0; i < 16; ++i) {
            int p = gw * 16 + i;
            int2   rc = rc_p[p];
            float2 rm = rm_p[p];
            float4 ea = ea_p[p];
            unsigned tw = tb32[rc.x + cp];
            unsigned uw = ub32[rc.y + cp];
            float t0 = __uint_as_float(tw << 16);
            float t1 = __uint_as_float(tw & 0xFFFF0000u);
            float u0 = __uint_as_float(uw << 16);
            float u1 = __uint_as_float(uw & 0xFFFF0000u);
            float base0 = rm.x * wr0 + ea.x * wa00 + ea.y * wa10 + ea.z * wa20 + ea.w * wa30 + b10;
            float base1 = rm.x * wr1 + ea.x * wa01 + ea.y * wa11 + ea.z * wa21 + ea.w * wa31 + b11;
            float v0 = silu_f(t0 + u0 + base0);
            float v1 = silu_f(t1 + u1 + base1);
            *(unsigned*)&VAw[i * BTS + c0] = f2bf2u(v0, v1);
        }

        // epilogue edge metadata for this wave's 16 edges
        int em0 = gw * 16 + quad * 4;
        int   r0 = rc_p[em0 + 0].x, r1 = rc_p[em0 + 1].x;   // scaled by 64
        int   r2 = rc_p[em0 + 2].x, r3 = rc_p[em0 + 3].x;
        float mk0 = rm_p[em0 + 0].y, mk1 = rm_p[em0 + 1].y;
        float mk2 = rm_p[em0 + 2].y, mk3 = rm_p[em0 + 3].y;

        __builtin_amdgcn_wave_barrier();           // keep writes above reads (compile-time)
        __builtin_amdgcn_s_waitcnt(0xc07f);        // lgkmcnt(0): all VA writes landed

        bf16x8 afr[4];
        #pragma unroll
        for (int kt = 0; kt < 4; ++kt)
            afr[kt] = *(const bf16x8*)&VAw[ln15 * BTS + kt * 32 + quad * 8];

        __builtin_amdgcn_wave_barrier();           // keep reads above next-iter writes

        #pragma unroll
        for (int ct = 0; ct < 8; ++ct) {
            f32x4 acc = {0.f, 0.f, 0.f, 0.f};
            #pragma unroll
            for (int kt = 0; kt < 4; ++kt) {
                bf16x8 bfr = *(const bf16x8*)&BT[(ct * 16 + ln15) * BTS + kt * 32 + quad * 8];
                acc = __builtin_amdgcn_mfma_f32_16x16x32_bf16(afr[kt], bfr, acc, 0, 0, 0);
            }
            int col = ct * 16 + ln15;
            float b2c = s_b2[col];
            float m0 = silu_f(acc[0] + b2c) * mk0;
            float m1 = silu_f(acc[1] + b2c) * mk1;
            float m2 = silu_f(acc[2] + b2c) * mk2;
            float m3 = silu_f(acc[3] + b2c) * mk3;
            // run-length segmented flush (rows CSR-sorted); agg idx = r_scaled*2 + col
            float run = m0;
            int cur = r0;
            if (r1 != cur) { atomicAdd(&agg[cur * 2 + col], run); run = 0.f; cur = r1; }
            run += m1;
            if (r2 != cur) { atomicAdd(&agg[cur * 2 + col], run); run = 0.f; cur = r2; }
            run += m2;
            if (r3 != cur) { atomicAdd(&agg[cur * 2 + col], run); run = 0.f; cur = r3; }
            run += m3;
            atomicAdd(&agg[cur * 2 + col], run);
        }
    }
}

// ---------------- node MLP layer 1 (persistent MFMA) ----------------
__global__ __launch_bounds__(512) void nk1_mfma(
    const float* __restrict__ h, const float* __restrict__ agg,
    const float* __restrict__ h0,
    const float* __restrict__ nw1_l, const float* __restrict__ nb1_l,
    short* __restrict__ qb)
{
    __shared__ __align__(16) short BT[64 * K1S];
    int c0 = blockIdx.y * 64;
    for (int i = threadIdx.x; i < 64 * 288; i += 512) {
        int c = i / 288, k = i - c * 288;
        BT[c * K1S + k] = (k < 267) ? f2bf(nw1_l[k * HD + c0 + c]) : (short)0;
    }
    int wv = threadIdx.x >> 6, lane = threadIdx.x & 63;
    int ln15 = lane & 15, quad = lane >> 4;
    __syncthreads();

    for (int g = blockIdx.x * 8 + wv; g < NG16; g += gridDim.x * 8) {
        int row = g * 16 + ln15;
        const float* hrow = h + row * HD;
        const float* arow = agg + row * HD;
        bf16x8 afr[9];
        #pragma unroll
        for (int kt = 0; kt < 4; ++kt) {
            float4 x0 = *(const float4*)(hrow + kt * 32 + quad * 8);
            float4 x1 = *(const float4*)(hrow + kt * 32 + quad * 8 + 4);
            afr[kt] = pack8(x0, x1);
        }
        #pragma unroll
        for (int kt = 0; kt < 4; ++kt) {
            float4 x0 = *(const float4*)(arow + kt * 32 + quad * 8);
            float4 x1 = *(const float4*)(arow + kt * 32 + quad * 8 + 4);
            afr[4 + kt] = pack8(x0, x1);
        }
        {
            bf16x8 a8 = {0, 0, 0, 0, 0, 0, 0, 0};
            if (quad == 0) {
                #pragma unroll
                for (int jj = 0; jj < 8; ++jj) a8[jj] = f2bf(h0[row * INN + jj]);
            } else if (quad == 1) {
                #pragma unroll
                for (int jj = 0; jj < 3; ++jj) a8[jj] = f2bf(h0[row * INN + 8 + jj]);
            }
            afr[8] = a8;
        }
        #pragma unroll
        for (int ct = 0; ct < 4; ++ct) {
            f32x4 acc = {0.f, 0.f, 0.f, 0.f};
            #pragma unroll
            for (int kt = 0; kt < 9; ++kt) {
                bf16x8 bfr = *(const bf16x8*)&BT[(ct * 16 + ln15) * K1S + kt * 32 + quad * 8];
                acc = __builtin_amdgcn_mfma_f32_16x16x32_bf16(afr[kt], bfr, acc, 0, 0, 0);
            }
            int col = c0 + ct * 16 + ln15;
            float b = nb1_l[col];
            #pragma unroll
            for (int r4 = 0; r4 < 4; ++r4) {
                int orow = g * 16 + quad * 4 + r4;
                qb[orow * HD + col] = f2bf(silu_f(acc[r4] + b));
            }
        }
    }
}

// ---------------- node MLP layer 2 + residual (persistent MFMA) ----------------
__global__ __launch_bounds__(512) void nk2_mfma(
    const short* __restrict__ qb, const float* __restrict__ nw2_l,
    const float* __restrict__ nb2_l, float* __restrict__ h)
{
    __shared__ __align__(16) short BT[128 * BTS];
    for (int i = threadIdx.x; i < 128 * 128; i += 512) {
        int c = i >> 7, k = i & 127;
        BT[c * BTS + k] = f2bf(nw2_l[k * HD + c]);
    }
    int wv = threadIdx.x >> 6, lane = threadIdx.x & 63;
    int ln15 = lane & 15, quad = lane >> 4;
    __syncthreads();

    for (int g = blockIdx.x * 8 + wv; g < NG16; g += gridDim.x * 8) {
        int row = g * 16 + ln15;
        bf16x8 afr[4];
        #pragma unroll
        for (int kt = 0; kt < 4; ++kt)
            afr[kt] = *(const bf16x8*)(qb + row * HD + kt * 32 + quad * 8);

        #pragma unroll
        for (int ct = 0; ct < 8; ++ct) {
            f32x4 acc = {0.f, 0.f, 0.f, 0.f};
            #pragma unroll
            for (int kt = 0; kt < 4; ++kt) {
                bf16x8 bfr = *(const bf16x8*)&BT[(ct * 16 + ln15) * BTS + kt * 32 + quad * 8];
                acc = __builtin_amdgcn_mfma_f32_16x16x32_bf16(afr[kt], bfr, acc, 0, 0, 0);
            }
            int col = ct * 16 + ln15;
            float b = nb2_l[col];
            #pragma unroll
            for (int r4 = 0; r4 < 4; ++r4) {
                int orow = g * 16 + quad * 4 + r4;
                h[orow * HD + col] += acc[r4] + b;
            }
        }
    }
}

extern "C" void kernel_launch(void* const* d_in, const int* in_sizes, int n_in,
                              void* d_out, int out_size, void* d_ws, size_t ws_size,
                              hipStream_t stream)
{
    const float* h0    = (const float*)d_in[0];
    const float* x     = (const float*)d_in[1];
    const int*   ei    = (const int*)d_in[2];
    const float* eattr = (const float*)d_in[3];
    const float* emask = (const float*)d_in[5];
    const float* emb_w = (const float*)d_in[7];
    const float* emb_b = (const float*)d_in[8];
    const float* ew1   = (const float*)d_in[9];
    const float* eb1   = (const float*)d_in[10];
    const float* ew2   = (const float*)d_in[11];
    const float* eb2   = (const float*)d_in[12];
    const float* nw1   = (const float*)d_in[13];
    const float* nb1   = (const float*)d_in[14];
    const float* nw2   = (const float*)d_in[15];
    const float* nb2   = (const float*)d_in[16];

    float* h = (float*)d_out;

    // workspace layout (~80.6 MB; d_ws >= 256 MiB)
    short*  tb     = (short*)d_ws;                         // NN*HD bf16
    short*  ub     = tb + (size_t)NN * HD;                 // NN*HD bf16
    float*  agg    = (float*)(ub + (size_t)NN * HD);       // NN*HD fp32
    short*  qb     = tb;                                   // alias (tb dead by nk1)
    int*    cnt    = (int*)(agg + (size_t)NN * HD);        // NN
    int*    rowptr = cnt + NN;                             // NN+1
    int*    cursor = rowptr + NN + 1;                      // NN
    int*    eidx   = cursor + NN;                          // NE
    int2*   rc_p   = (int2*)(eidx + NE);                   // NE int2
    float2* rm_p   = (float2*)(rc_p + NE);                 // NE float2
    float4* ea_p   = (float4*)(rm_p + NE);                 // NE float4

    csr_zero<<<(NN + 255) / 256, 256, 0, stream>>>(cnt);
    csr_hist<<<NE / 256, 256, 0, stream>>>(ei, cnt);
    csr_scan<<<1, 1024, 0, stream>>>(cnt, rowptr, cursor);
    csr_fill<<<NE / 256, 256, 0, stream>>>(ei, cursor, eidx);
    edge_pre<<<NE / 256, 256, 0, stream>>>(ei, eidx, x, eattr, emask, rc_p, rm_p, ea_p);

    embed_kernel<<<(NN * HD + 255) / 256, 256, 0, stream>>>(h0, emb_w, emb_b, h);

    dim3 gtu(128, 2);
    dim3 gn1(128, 2);
    for (int l = 0; l < NL; ++l) {
        tu_mfma<<<gtu, 512, 0, stream>>>(h, ew1 + l * 261 * HD, tb, ub);
        zero_kernel<<<(NN * HD / 4 + 255) / 256, 256, 0, stream>>>((float4*)agg, NN * HD / 4);
        edge_m_kernel<<<768, 256, 0, stream>>>(tb, ub, rc_p, rm_p, ea_p,
            ew1 + l * 261 * HD, eb1 + l * HD, ew2 + l * HD * HD, eb2 + l * HD, agg);
        nk1_mfma<<<gn1, 512, 0, stream>>>(h, agg, h0,
            nw1 + l * 267 * HD, nb1 + l * HD, qb);
        nk2_mfma<<<128, 512, 0, stream>>>(qb, nw2 + l * HD * HD, nb2 + l * HD, h);
    }
}